// Round 8
// baseline (237.403 us; speedup 1.0000x reference)
//
#include <hip/hip_runtime.h>
#include <hip/hip_bf16.h>

#define EMBED 128
#define HEADS 8
#define DH 16
#define FFN 512
#define BB 16
#define NN 256
#define GRID_B1 2048

typedef float floatx4 __attribute__((ext_vector_type(4)));

// ---------------- Kernel A: LN1 + QKV projection (one block per row) -------
__global__ __launch_bounds__(128) void ln1_qkv_kernel(
    const float* __restrict__ x,
    const float* __restrict__ ln1_g, const float* __restrict__ ln1_b,
    const float* __restrict__ Wq, const float* __restrict__ bq,
    const float* __restrict__ Wk, const float* __restrict__ bk,
    const float* __restrict__ Wv, const float* __restrict__ bv,
    float* __restrict__ q, float* __restrict__ k, float* __restrict__ v)
{
    const int row = blockIdx.x;          // b*N + i
    const int e = threadIdx.x;           // 0..127
    __shared__ float red[128];
    __shared__ float xn[128];

    float xv = x[(size_t)row * EMBED + e];

    red[e] = xv;
    __syncthreads();
    for (int s = 64; s > 0; s >>= 1) { if (e < s) red[e] += red[e + s]; __syncthreads(); }
    float mu = red[0] * (1.0f / EMBED);
    __syncthreads();
    float d = xv - mu;
    red[e] = d * d;
    __syncthreads();
    for (int s = 64; s > 0; s >>= 1) { if (e < s) red[e] += red[e + s]; __syncthreads(); }
    float var = red[0] * (1.0f / EMBED);
    float rs = rsqrtf(var + 1e-5f);
    xn[e] = d * rs * ln1_g[e] + ln1_b[e];
    __syncthreads();

    float aq = bq[e], ak = bk[e], av = bv[e];
    #pragma unroll 8
    for (int c = 0; c < EMBED; ++c) {
        float xc = xn[c];
        aq += xc * Wq[c * EMBED + e];
        ak += xc * Wk[c * EMBED + e];
        av += xc * Wv[c * EMBED + e];
    }
    size_t o = (size_t)row * EMBED + e;
    q[o] = aq; k[o] = ak; v[o] = av;
}

// ---- Kernel B1: s_full[bi][j][h] = 0.25 * q.(k + pe)  (grid-stride) -------
// Wave reads pe EXACTLY like a copy kernel: lane l -> float4 at u*512B+16*l.
// Dense ~8 MB instantaneous window across the grid (anti-camping test).
__global__ __launch_bounds__(256) void qkpe_dot_kernel(
    const float* __restrict__ pe,
    const float* __restrict__ q, const float* __restrict__ k,
    float* __restrict__ s_full)
{
    const int t    = threadIdx.x;
    const int lane = t & 63;
    const int wave = t >> 6;          // 0..3
    const int usel = lane >> 5;       // which of the wave's 2 units
    const int l31  = lane & 31;       // l31 = h*8/2... 4*l31 = h*16 + c*4
    const int h    = l31 >> 2;

    size_t u = (size_t)blockIdx.x * 8 + wave * 2 + usel;
    const size_t stride = (size_t)GRID_B1 * 8;   // 16384 units/sweep

    #pragma unroll 4
    for (int it = 0; it < 64; ++it) {
        const size_t bi = u >> 8;           // b*N + i
        const size_t j  = u & 255;
        const size_t b  = u >> 16;

        const floatx4 p4 = *reinterpret_cast<const floatx4*>(pe + u * 128 + 4 * l31);
        const floatx4 q4 = *reinterpret_cast<const floatx4*>(q + bi * 128 + 4 * l31);
        const floatx4 k4 = *reinterpret_cast<const floatx4*>(k + (b * 256 + j) * 128 + 4 * l31);
        const floatx4 sum = k4 + p4;
        float s = q4.x * sum.x + q4.y * sum.y + q4.z * sum.z + q4.w * sum.w;
        s += __shfl_xor(s, 1);
        s += __shfl_xor(s, 2);
        if ((l31 & 3) == 0) s_full[u * 8 + h] = s * 0.25f;   // 1/sqrt(16)
        u += stride;
    }
}

// ---- Kernel B2: per-row softmax over s_full + mask -> probs ---------------
__global__ __launch_bounds__(256) void softmax_kernel(
    const float* __restrict__ s_full,
    const float* __restrict__ mask,
    float* __restrict__ probs)
{
    const int row = blockIdx.x;      // bi
    const int t   = threadIdx.x;
    const int g   = t >> 5;          // head
    const int l5  = t & 31;

    __shared__ float sc[NN * 9];     // [j][h] padded stride 9 (conflict-free)
    __shared__ float msk[NN];

    msk[t] = mask[(size_t)row * NN + t];
    const float* srow = s_full + (size_t)row * (NN * HEADS);
    #pragma unroll
    for (int p = 0; p < 8; ++p) {
        const int idx = t + 256 * p;             // j*8 + h
        sc[(idx >> 3) * 9 + (idx & 7)] = srow[idx];
    }
    __syncthreads();

    float vals[8];
    float m = -1e30f;
    #pragma unroll
    for (int r = 0; r < 8; ++r) {
        vals[r] = sc[(l5 + 32 * r) * 9 + g] + msk[l5 + 32 * r];
        m = fmaxf(m, vals[r]);
    }
    #pragma unroll
    for (int off = 16; off >= 1; off >>= 1) m = fmaxf(m, __shfl_xor(m, off));
    float ssum = 0.f;
    #pragma unroll
    for (int r = 0; r < 8; ++r) { float e2 = __expf(vals[r] - m); vals[r] = e2; ssum += e2; }
    #pragma unroll
    for (int off = 16; off >= 1; off >>= 1) ssum += __shfl_xor(ssum, off);
    const float inv = 1.0f / ssum;
    float* pout = probs + ((size_t)row * HEADS + g) * NN;
    #pragma unroll
    for (int r = 0; r < 8; ++r) pout[l5 + 32 * r] = vals[r] * inv;
}

// ---- Kernel C: PV + Wo + residual + LN2 + FFN + residual ------------------
__global__ __launch_bounds__(256) void pv_ffn_kernel(
    const float* __restrict__ x,
    const float* __restrict__ probs,
    const float* __restrict__ v,
    const float* __restrict__ Wo, const float* __restrict__ bo,
    const float* __restrict__ ln2_g, const float* __restrict__ ln2_b,
    const float* __restrict__ W1, const float* __restrict__ b1,
    const float* __restrict__ W2, const float* __restrict__ b2,
    float* __restrict__ out)
{
    const int blk  = blockIdx.x;
    const int b    = blk >> 6;
    const int row0 = b * NN + ((blk & 63) << 2);
    const int t    = threadIdx.x;

    __shared__ float ctx[4][EMBED];
    __shared__ float x2s[4][EMBED];
    __shared__ float xn2[4][EMBED];
    __shared__ float hb[4][FFN];
    __shared__ float red4[4][4][EMBED];
    __shared__ float mus[4], rss[4];

    const int e4  = t & 31;
    const int grp = t >> 5;

    {
        const int seg = grp;
        const int h   = e4 >> 2;
        float4 a0 = {0,0,0,0}, a1 = a0, a2 = a0, a3 = a0;
        const float* vb = v + ((size_t)(b * NN + seg * 32)) * EMBED + 4 * e4;
        const size_t p0o = ((size_t)(row0 + 0) * HEADS + h) * NN + seg * 32;
        const size_t p1o = ((size_t)(row0 + 1) * HEADS + h) * NN + seg * 32;
        const size_t p2o = ((size_t)(row0 + 2) * HEADS + h) * NN + seg * 32;
        const size_t p3o = ((size_t)(row0 + 3) * HEADS + h) * NN + seg * 32;
        #pragma unroll 4
        for (int jj = 0; jj < 32; ++jj) {
            const float4 v4 = *reinterpret_cast<const float4*>(vb + (size_t)jj * EMBED);
            const float p0 = probs[p0o + jj];
            const float p1 = probs[p1o + jj];
            const float p2 = probs[p2o + jj];
            const float p3 = probs[p3o + jj];
            a0.x += p0*v4.x; a0.y += p0*v4.y; a0.z += p0*v4.z; a0.w += p0*v4.w;
            a1.x += p1*v4.x; a1.y += p1*v4.y; a1.z += p1*v4.z; a1.w += p1*v4.w;
            a2.x += p2*v4.x; a2.y += p2*v4.y; a2.z += p2*v4.z; a2.w += p2*v4.w;
            a3.x += p3*v4.x; a3.y += p3*v4.y; a3.z += p3*v4.z; a3.w += p3*v4.w;
        }
        a0.x += __shfl_xor(a0.x, 32); a0.y += __shfl_xor(a0.y, 32);
        a0.z += __shfl_xor(a0.z, 32); a0.w += __shfl_xor(a0.w, 32);
        a1.x += __shfl_xor(a1.x, 32); a1.y += __shfl_xor(a1.y, 32);
        a1.z += __shfl_xor(a1.z, 32); a1.w += __shfl_xor(a1.w, 32);
        a2.x += __shfl_xor(a2.x, 32); a2.y += __shfl_xor(a2.y, 32);
        a2.z += __shfl_xor(a2.z, 32); a2.w += __shfl_xor(a2.w, 32);
        a3.x += __shfl_xor(a3.x, 32); a3.y += __shfl_xor(a3.y, 32);
        a3.z += __shfl_xor(a3.z, 32); a3.w += __shfl_xor(a3.w, 32);
        if ((t & 63) < 32) {
            const int w = t >> 6;
            *reinterpret_cast<float4*>(&red4[w][0][4 * e4]) = a0;
            *reinterpret_cast<float4*>(&red4[w][1][4 * e4]) = a1;
            *reinterpret_cast<float4*>(&red4[w][2][4 * e4]) = a2;
            *reinterpret_cast<float4*>(&red4[w][3][4 * e4]) = a3;
        }
    }
    __syncthreads();
    if (t < 128) {
        #pragma unroll
        for (int r = 0; r < 4; ++r)
            ctx[r][t] = red4[0][r][t] + red4[1][r][t] + red4[2][r][t] + red4[3][r][t];
    }
    __syncthreads();

    {
        const int r = grp & 3, ch = grp >> 2;
        float4 wacc = {0,0,0,0};
        const float* Wob = Wo + ch * 64 * EMBED + 4 * e4;
        #pragma unroll 8
        for (int cc = 0; cc < 64; ++cc) {
            const float4 w4 = *reinterpret_cast<const float4*>(Wob + (size_t)cc * EMBED);
            const float xc = ctx[r][ch * 64 + cc];
            wacc.x += xc*w4.x; wacc.y += xc*w4.y; wacc.z += xc*w4.z; wacc.w += xc*w4.w;
        }
        *reinterpret_cast<float4*>(&red4[ch][r][4 * e4]) = wacc;
    }
    __syncthreads();
    {
        #pragma unroll
        for (int rr = 0; rr < 2; ++rr) {
            const int idx = t + 256 * rr;
            const int r = idx >> 7, e = idx & 127;
            x2s[r][e] = red4[0][r][e] + red4[1][r][e] + bo[e]
                      + x[(size_t)(row0 + r) * EMBED + e];
        }
    }
    __syncthreads();

    {
        const int wid = t >> 6, l64 = t & 63;
        const float v0 = x2s[wid][l64], v1 = x2s[wid][l64 + 64];
        float s = v0 + v1;
        float sq = v0 * v0 + v1 * v1;
        #pragma unroll
        for (int off = 32; off >= 1; off >>= 1) {
            s  += __shfl_xor(s, off);
            sq += __shfl_xor(sq, off);
        }
        if (l64 == 0) {
            const float mu = s * (1.0f / EMBED);
            const float var = sq * (1.0f / EMBED) - mu * mu;
            mus[wid] = mu;
            rss[wid] = rsqrtf(var + 1e-5f);
        }
    }
    __syncthreads();
    {
        #pragma unroll
        for (int rr = 0; rr < 2; ++rr) {
            const int idx = t + 256 * rr;
            const int r = idx >> 7, e = idx & 127;
            xn2[r][e] = (x2s[r][e] - mus[r]) * rss[r] * ln2_g[e] + ln2_b[e];
        }
    }
    __syncthreads();

    {
        const int f4 = t & 127, rh = t >> 7;
        const int r0 = 2 * rh, r1 = r0 + 1;
        float4 h0 = *reinterpret_cast<const float4*>(&b1[4 * f4]);
        float4 h1 = h0;
        const float* W1b = W1 + 4 * f4;
        #pragma unroll 8
        for (int c = 0; c < 128; ++c) {
            const float4 w4 = *reinterpret_cast<const float4*>(W1b + (size_t)c * FFN);
            const float xa = xn2[r0][c], xb = xn2[r1][c];
            h0.x += xa*w4.x; h0.y += xa*w4.y; h0.z += xa*w4.z; h0.w += xa*w4.w;
            h1.x += xb*w4.x; h1.y += xb*w4.y; h1.z += xb*w4.z; h1.w += xb*w4.w;
        }
        h0.x = fmaxf(h0.x, 0.f); h0.y = fmaxf(h0.y, 0.f);
        h0.z = fmaxf(h0.z, 0.f); h0.w = fmaxf(h0.w, 0.f);
        h1.x = fmaxf(h1.x, 0.f); h1.y = fmaxf(h1.y, 0.f);
        h1.z = fmaxf(h1.z, 0.f); h1.w = fmaxf(h1.w, 0.f);
        *reinterpret_cast<float4*>(&hb[r0][4 * f4]) = h0;
        *reinterpret_cast<float4*>(&hb[r1][4 * f4]) = h1;
    }
    __syncthreads();

    {
        const int r = grp & 3, fq = grp >> 2;
        float4 facc = {0,0,0,0};
        const float* W2b = W2 + (size_t)fq * 256 * EMBED + 4 * e4;
        #pragma unroll 8
        for (int ff = 0; ff < 256; ++ff) {
            const float4 w4 = *reinterpret_cast<const float4*>(W2b + (size_t)ff * EMBED);
            const float hv = hb[r][fq * 256 + ff];
            facc.x += hv*w4.x; facc.y += hv*w4.y; facc.z += hv*w4.z; facc.w += hv*w4.w;
        }
        *reinterpret_cast<float4*>(&red4[fq][r][4 * e4]) = facc;
    }
    __syncthreads();
    {
        #pragma unroll
        for (int rr = 0; rr < 2; ++rr) {
            const int idx = t + 256 * rr;
            const int r = idx >> 7, e = idx & 127;
            out[(size_t)(row0 + r) * EMBED + e] =
                x2s[r][e] + b2[e] + red4[0][r][e] + red4[1][r][e];
        }
    }
}

extern "C" void kernel_launch(void* const* d_in, const int* in_sizes, int n_in,
                              void* d_out, int out_size, void* d_ws, size_t ws_size,
                              hipStream_t stream) {
    const float* x    = (const float*)d_in[0];
    const float* pe   = (const float*)d_in[1];
    const float* mask = (const float*)d_in[2];
    const float* ln1g = (const float*)d_in[3];
    const float* ln1b = (const float*)d_in[4];
    const float* Wq   = (const float*)d_in[5];
    const float* bq   = (const float*)d_in[6];
    const float* Wk   = (const float*)d_in[7];
    const float* bk   = (const float*)d_in[8];
    const float* Wv   = (const float*)d_in[9];
    const float* bv   = (const float*)d_in[10];
    const float* Wo   = (const float*)d_in[11];
    const float* bo   = (const float*)d_in[12];
    const float* ln2g = (const float*)d_in[13];
    const float* ln2b = (const float*)d_in[14];
    const float* W1   = (const float*)d_in[15];
    const float* b1   = (const float*)d_in[16];
    const float* W2   = (const float*)d_in[17];
    const float* b2   = (const float*)d_in[18];
    float* out = (float*)d_out;

    float* q      = (float*)d_ws;
    float* kk     = q      + (size_t)BB * NN * EMBED;
    float* vv     = kk     + (size_t)BB * NN * EMBED;
    float* probs  = vv     + (size_t)BB * NN * EMBED;        // 33.5 MB
    float* s_full = probs  + (size_t)BB * NN * HEADS * NN;   // 33.5 MB

    ln1_qkv_kernel<<<BB * NN, 128, 0, stream>>>(x, ln1g, ln1b, Wq, bq, Wk, bk, Wv, bv, q, kk, vv);
    qkpe_dot_kernel<<<GRID_B1, 256, 0, stream>>>(pe, q, kk, s_full);
    softmax_kernel<<<BB * NN, 256, 0, stream>>>(s_full, mask, probs);
    pv_ffn_kernel<<<BB * NN / 4, 256, 0, stream>>>(x, probs, vv, Wo, bo,
                                                   ln2g, ln2b, W1, b1, W2, b2, out);
}

// Round 9
// 220.361 us; speedup vs baseline: 1.0773x; 1.0773x over previous
//
#include <hip/hip_runtime.h>
#include <hip/hip_bf16.h>

#define EMBED 128
#define HEADS 8
#define DH 16
#define FFN 512
#define BB 16
#define NN 256

typedef float floatx4 __attribute__((ext_vector_type(4)));

// ---------------- Kernel A: LN1 + QKV projection (one block per row) -------
__global__ __launch_bounds__(128) void ln1_qkv_kernel(
    const float* __restrict__ x,
    const float* __restrict__ ln1_g, const float* __restrict__ ln1_b,
    const float* __restrict__ Wq, const float* __restrict__ bq,
    const float* __restrict__ Wk, const float* __restrict__ bk,
    const float* __restrict__ Wv, const float* __restrict__ bv,
    float* __restrict__ q, float* __restrict__ k, float* __restrict__ v)
{
    const int row = blockIdx.x;          // b*N + i
    const int e = threadIdx.x;           // 0..127
    __shared__ float red[128];
    __shared__ float xn[128];

    float xv = x[(size_t)row * EMBED + e];

    red[e] = xv;
    __syncthreads();
    for (int s = 64; s > 0; s >>= 1) { if (e < s) red[e] += red[e + s]; __syncthreads(); }
    float mu = red[0] * (1.0f / EMBED);
    __syncthreads();
    float d = xv - mu;
    red[e] = d * d;
    __syncthreads();
    for (int s = 64; s > 0; s >>= 1) { if (e < s) red[e] += red[e + s]; __syncthreads(); }
    float var = red[0] * (1.0f / EMBED);
    float rs = rsqrtf(var + 1e-5f);
    xn[e] = d * rs * ln1_g[e] + ln1_b[e];
    __syncthreads();

    float aq = bq[e], ak = bk[e], av = bv[e];
    #pragma unroll 8
    for (int c = 0; c < EMBED; ++c) {
        float xc = xn[c];
        aq += xc * Wq[c * EMBED + e];
        ak += xc * Wk[c * EMBED + e];
        av += xc * Wv[c * EMBED + e];
    }
    size_t o = (size_t)row * EMBED + e;
    q[o] = aq; k[o] = ak; v[o] = av;
}

// ---- Kernel B: scores + softmax -> probs (R7 structure, at read ceiling) --
__global__ __launch_bounds__(256) void scores_softmax_kernel(
    const float* __restrict__ pe,
    const float* __restrict__ mask,
    const float* __restrict__ q, const float* __restrict__ k,
    float* __restrict__ probs)
{
    const int bid = blockIdx.x;
    const int row = (bid & 7) * (BB * NN / 8) + (bid >> 3);  // bijective
    const int bb  = row >> 8;        // N = 256
    const int t   = threadIdx.x;     // 0..255

    __shared__ float sc[HEADS][260];
    __shared__ float qs[EMBED];
    __shared__ float msk[NN];

    if (t < EMBED) qs[t] = q[(size_t)row * EMBED + t];
    msk[t] = mask[(size_t)row * NN + t];
    __syncthreads();

    const int g = t >> 5;
    const int l = t & 31;
    float4 q4 = *reinterpret_cast<const float4*>(&qs[4 * l]);

    const size_t pe_row = (size_t)row * NN * EMBED;
    const size_t k_row  = (size_t)bb * NN * EMBED;
    const int rot = row & 31;

    #pragma unroll 8
    for (int jt0 = 0; jt0 < 32; ++jt0) {
        const int jt = (jt0 + rot) & 31;
        const int j  = jt * 8 + g;
        const floatx4 p4 = __builtin_nontemporal_load(
            reinterpret_cast<const floatx4*>(pe + pe_row + (size_t)j * EMBED + 4 * l));
        const float4 k4 = *reinterpret_cast<const float4*>(k + k_row + (size_t)j * EMBED + 4 * l);
        float s = q4.x * (k4.x + p4.x) + q4.y * (k4.y + p4.y)
                + q4.z * (k4.z + p4.z) + q4.w * (k4.w + p4.w);
        s += __shfl_xor(s, 1);
        s += __shfl_xor(s, 2);
        if ((l & 3) == 0) {
            sc[l >> 2][j] = s * 0.25f;
        }
    }
    __syncthreads();

    {
        float vals[8];
        float m = -1e30f;
        #pragma unroll
        for (int r = 0; r < 8; ++r) {
            vals[r] = sc[g][l + 32 * r] + msk[l + 32 * r];
            m = fmaxf(m, vals[r]);
        }
        #pragma unroll
        for (int off = 16; off >= 1; off >>= 1) m = fmaxf(m, __shfl_xor(m, off));
        float ssum = 0.f;
        #pragma unroll
        for (int r = 0; r < 8; ++r) { float e2 = __expf(vals[r] - m); vals[r] = e2; ssum += e2; }
        #pragma unroll
        for (int off = 16; off >= 1; off >>= 1) ssum += __shfl_xor(ssum, off);
        float inv = 1.0f / ssum;
        float* pout = probs + ((size_t)row * HEADS + g) * NN;
        #pragma unroll
        for (int r = 0; r < 8; ++r) pout[l + 32 * r] = vals[r] * inv;
    }
}

// ---- Kernel C: PV + Wo + residual + LN2 + FFN + residual (8 rows/block) ---
__global__ __launch_bounds__(256) void pv_ffn_kernel(
    const float* __restrict__ x,
    const float* __restrict__ probs,
    const float* __restrict__ v,
    const float* __restrict__ Wo, const float* __restrict__ bo,
    const float* __restrict__ ln2_g, const float* __restrict__ ln2_b,
    const float* __restrict__ W1, const float* __restrict__ b1,
    const float* __restrict__ W2, const float* __restrict__ b2,
    float* __restrict__ out)
{
    const int blk  = blockIdx.x;         // 0..511
    const int b    = blk >> 5;           // 32 blocks per batch
    const int row0 = b * NN + ((blk & 31) << 3);   // first of 8 rows
    const int t    = threadIdx.x;        // 0..255

    __shared__ float ctx[8][EMBED];      // 4 KB
    __shared__ float x2s[8][EMBED];      // 4 KB
    __shared__ float xn2[8][EMBED];      // 4 KB
    __shared__ float hb[8][FFN];         // 16 KB
    __shared__ float red[4][8][EMBED];   // 16 KB
    __shared__ float mus[8], rss[8];

    // ---- P1: PV. thread (e4 = t&31, jseg = t>>5). float4 over e and j. ----
    {
        const int e4   = t & 31;
        const int jseg = t >> 5;
        const int h    = e4 >> 2;
        floatx4 acc[8];
        #pragma unroll
        for (int r = 0; r < 8; ++r) acc[r] = (floatx4){0,0,0,0};

        const float* vb = v + ((size_t)(b * NN + jseg * 32)) * EMBED + 4 * e4;
        const float* pb = probs + ((size_t)row0 * HEADS + h) * NN + jseg * 32;

        #pragma unroll 2
        for (int jc = 0; jc < 8; ++jc) {
            const floatx4 v0 = *reinterpret_cast<const floatx4*>(vb + (size_t)(jc*4+0) * EMBED);
            const floatx4 v1 = *reinterpret_cast<const floatx4*>(vb + (size_t)(jc*4+1) * EMBED);
            const floatx4 v2 = *reinterpret_cast<const floatx4*>(vb + (size_t)(jc*4+2) * EMBED);
            const floatx4 v3 = *reinterpret_cast<const floatx4*>(vb + (size_t)(jc*4+3) * EMBED);
            #pragma unroll
            for (int r = 0; r < 8; ++r) {
                const floatx4 p4 = *reinterpret_cast<const floatx4*>(pb + (size_t)r * (HEADS*NN) + jc*4);
                acc[r] += p4.x * v0 + p4.y * v1 + p4.z * v2 + p4.w * v3;
            }
        }
        // combine jseg pairs (t ^ 32)
        #pragma unroll
        for (int r = 0; r < 8; ++r) {
            acc[r].x += __shfl_xor(acc[r].x, 32);
            acc[r].y += __shfl_xor(acc[r].y, 32);
            acc[r].z += __shfl_xor(acc[r].z, 32);
            acc[r].w += __shfl_xor(acc[r].w, 32);
        }
        if ((t & 63) < 32) {
            const int w = t >> 6;
            #pragma unroll
            for (int r = 0; r < 8; ++r)
                *reinterpret_cast<floatx4*>(&red[w][r][4 * e4]) = acc[r];
        }
    }
    __syncthreads();
    {
        #pragma unroll
        for (int rr = 0; rr < 4; ++rr) {
            const int idx = t + 256 * rr;        // 0..1023 = r*128+e
            const int r = idx >> 7, e = idx & 127;
            ctx[r][e] = red[0][r][e] + red[1][r][e] + red[2][r][e] + red[3][r][e];
        }
    }
    __syncthreads();

    // ---- P2: Wo + residual. thread (e = t&127, half = t>>7 -> 4 rows) -----
    {
        const int e = t & 127, half = t >> 7;
        const int r0 = half * 4;
        float a0 = 0.f, a1 = 0.f, a2 = 0.f, a3 = 0.f;
        #pragma unroll 4
        for (int c = 0; c < EMBED; ++c) {
            const float w = Wo[c * EMBED + e];
            a0 += ctx[r0 + 0][c] * w;
            a1 += ctx[r0 + 1][c] * w;
            a2 += ctx[r0 + 2][c] * w;
            a3 += ctx[r0 + 3][c] * w;
        }
        const float bv_ = bo[e];
        x2s[r0 + 0][e] = a0 + bv_ + x[(size_t)(row0 + r0 + 0) * EMBED + e];
        x2s[r0 + 1][e] = a1 + bv_ + x[(size_t)(row0 + r0 + 1) * EMBED + e];
        x2s[r0 + 2][e] = a2 + bv_ + x[(size_t)(row0 + r0 + 2) * EMBED + e];
        x2s[r0 + 3][e] = a3 + bv_ + x[(size_t)(row0 + r0 + 3) * EMBED + e];
    }
    __syncthreads();

    // ---- P3: LN2. wave w reduces rows 2w and 2w+1 -------------------------
    {
        const int wid = t >> 6, l64 = t & 63;
        #pragma unroll
        for (int rr = 0; rr < 2; ++rr) {
            const int row = wid * 2 + rr;
            const float v0 = x2s[row][l64], v1 = x2s[row][l64 + 64];
            float s = v0 + v1;
            float sq = v0 * v0 + v1 * v1;
            #pragma unroll
            for (int off = 32; off >= 1; off >>= 1) {
                s  += __shfl_xor(s, off);
                sq += __shfl_xor(sq, off);
            }
            if (l64 == 0) {
                const float mu = s * (1.0f / EMBED);
                const float var = sq * (1.0f / EMBED) - mu * mu;
                mus[row] = mu;
                rss[row] = rsqrtf(var + 1e-5f);
            }
        }
    }
    __syncthreads();
    {
        #pragma unroll
        for (int rr = 0; rr < 4; ++rr) {
            const int idx = t + 256 * rr;
            const int r = idx >> 7, e = idx & 127;
            xn2[r][e] = (x2s[r][e] - mus[r]) * rss[r] * ln2_g[e] + ln2_b[e];
        }
    }
    __syncthreads();

    // ---- P4: FFN1. thread t covers f = t and t+256; all 8 rows ------------
    {
        float h0[8], h1[8];
        const float b0_ = b1[t], b1_ = b1[t + 256];
        #pragma unroll
        for (int r = 0; r < 8; ++r) { h0[r] = b0_; h1[r] = b1_; }
        #pragma unroll 2
        for (int c = 0; c < EMBED; ++c) {
            const float w0 = W1[c * FFN + t];
            const float w1 = W1[c * FFN + t + 256];
            #pragma unroll
            for (int r = 0; r < 8; ++r) {
                const float xc = xn2[r][c];
                h0[r] += xc * w0;
                h1[r] += xc * w1;
            }
        }
        #pragma unroll
        for (int r = 0; r < 8; ++r) {
            hb[r][t]       = fmaxf(h0[r], 0.f);
            hb[r][t + 256] = fmaxf(h1[r], 0.f);
        }
    }
    __syncthreads();

    // ---- P5: FFN2 + residual. thread (e = t&127, half -> 4 rows) ----------
    {
        const int e = t & 127, half = t >> 7;
        const int r0 = half * 4;
        float a0 = 0.f, a1 = 0.f, a2 = 0.f, a3 = 0.f;
        #pragma unroll 4
        for (int f = 0; f < FFN; ++f) {
            const float w = W2[f * EMBED + e];
            a0 += hb[r0 + 0][f] * w;
            a1 += hb[r0 + 1][f] * w;
            a2 += hb[r0 + 2][f] * w;
            a3 += hb[r0 + 3][f] * w;
        }
        const float bv_ = b2[e];
        out[(size_t)(row0 + r0 + 0) * EMBED + e] = x2s[r0 + 0][e] + bv_ + a0;
        out[(size_t)(row0 + r0 + 1) * EMBED + e] = x2s[r0 + 1][e] + bv_ + a1;
        out[(size_t)(row0 + r0 + 2) * EMBED + e] = x2s[r0 + 2][e] + bv_ + a2;
        out[(size_t)(row0 + r0 + 3) * EMBED + e] = x2s[r0 + 3][e] + bv_ + a3;
    }
}

extern "C" void kernel_launch(void* const* d_in, const int* in_sizes, int n_in,
                              void* d_out, int out_size, void* d_ws, size_t ws_size,
                              hipStream_t stream) {
    const float* x    = (const float*)d_in[0];
    const float* pe   = (const float*)d_in[1];
    const float* mask = (const float*)d_in[2];
    const float* ln1g = (const float*)d_in[3];
    const float* ln1b = (const float*)d_in[4];
    const float* Wq   = (const float*)d_in[5];
    const float* bq   = (const float*)d_in[6];
    const float* Wk   = (const float*)d_in[7];
    const float* bk   = (const float*)d_in[8];
    const float* Wv   = (const float*)d_in[9];
    const float* bv   = (const float*)d_in[10];
    const float* Wo   = (const float*)d_in[11];
    const float* bo   = (const float*)d_in[12];
    const float* ln2g = (const float*)d_in[13];
    const float* ln2b = (const float*)d_in[14];
    const float* W1   = (const float*)d_in[15];
    const float* b1   = (const float*)d_in[16];
    const float* W2   = (const float*)d_in[17];
    const float* b2   = (const float*)d_in[18];
    float* out = (float*)d_out;

    float* q     = (float*)d_ws;
    float* kk    = q  + (size_t)BB * NN * EMBED;
    float* vv    = kk + (size_t)BB * NN * EMBED;
    float* probs = vv + (size_t)BB * NN * EMBED;   // 33.5 MB

    ln1_qkv_kernel<<<BB * NN, 128, 0, stream>>>(x, ln1g, ln1b, Wq, bq, Wk, bk, Wv, bv, q, kk, vv);
    scores_softmax_kernel<<<BB * NN, 256, 0, stream>>>(pe, mask, q, kk, probs);
    pv_ffn_kernel<<<BB * NN / 8, 256, 0, stream>>>(x, probs, vv, Wo, bo,
                                                   ln2g, ln2b, W1, b1, W2, b2, out);
}

// Round 10
// 202.012 us; speedup vs baseline: 1.1752x; 1.0908x over previous
//
#include <hip/hip_runtime.h>
#include <hip/hip_bf16.h>

#define EMBED 128
#define HEADS 8
#define DH 16
#define FFN 512
#define BB 16
#define NN 256

typedef float floatx4 __attribute__((ext_vector_type(4)));

// ---- Kernel A: LN1 + QKV, 8 rows/block (weights read once per 8 rows) -----
__global__ __launch_bounds__(128) void ln1_qkv_kernel(
    const float* __restrict__ x,
    const float* __restrict__ ln1_g, const float* __restrict__ ln1_b,
    const float* __restrict__ Wq, const float* __restrict__ bq,
    const float* __restrict__ Wk, const float* __restrict__ bk,
    const float* __restrict__ Wv, const float* __restrict__ bv,
    float* __restrict__ q, float* __restrict__ k, float* __restrict__ v)
{
    const int row0 = blockIdx.x * 8;     // 512 blocks
    const int t    = threadIdx.x;        // 0..127
    const int wv_  = t >> 6;             // wave 0..1
    const int l64  = t & 63;

    __shared__ float xn[8][EMBED];

    // LN1: wave w handles rows 4w..4w+3; butterfly gives all lanes mu/rs
    #pragma unroll
    for (int rr = 0; rr < 4; ++rr) {
        const int r = wv_ * 4 + rr;
        const float v0 = x[(size_t)(row0 + r) * EMBED + l64];
        const float v1 = x[(size_t)(row0 + r) * EMBED + 64 + l64];
        float s  = v0 + v1;
        float sq = v0 * v0 + v1 * v1;
        #pragma unroll
        for (int off = 32; off >= 1; off >>= 1) {
            s  += __shfl_xor(s, off);
            sq += __shfl_xor(sq, off);
        }
        const float mu  = s * (1.0f / EMBED);
        const float var = sq * (1.0f / EMBED) - mu * mu;
        const float rs  = rsqrtf(var + 1e-5f);
        xn[r][l64]      = (v0 - mu) * rs * ln1_g[l64]      + ln1_b[l64];
        xn[r][l64 + 64] = (v1 - mu) * rs * ln1_g[l64 + 64] + ln1_b[l64 + 64];
    }
    __syncthreads();

    const int e = t;
    float aq[8], ak[8], av[8];
    const float bqe = bq[e], bke = bk[e], bve = bv[e];
    #pragma unroll
    for (int r = 0; r < 8; ++r) { aq[r] = bqe; ak[r] = bke; av[r] = bve; }

    #pragma unroll 4
    for (int c = 0; c < EMBED; ++c) {
        const float wq = Wq[c * EMBED + e];
        const float wk = Wk[c * EMBED + e];
        const float wv2 = Wv[c * EMBED + e];
        #pragma unroll
        for (int r = 0; r < 8; ++r) {
            const float xc = xn[r][c];
            aq[r] += xc * wq;
            ak[r] += xc * wk;
            av[r] += xc * wv2;
        }
    }
    #pragma unroll
    for (int r = 0; r < 8; ++r) {
        const size_t o = (size_t)(row0 + r) * EMBED + e;
        q[o] = aq[r]; k[o] = ak[r]; v[o] = av[r];
    }
}

// ---- Kernel B: scores + softmax -> probs (bf16) ----------------------------
// R7 structure: rotation + XCD swizzle; at the ~4.4 TB/s read ceiling.
__global__ __launch_bounds__(256) void scores_softmax_kernel(
    const float* __restrict__ pe,
    const float* __restrict__ mask,
    const float* __restrict__ q, const float* __restrict__ k,
    __hip_bfloat16* __restrict__ probs)
{
    const int bid = blockIdx.x;
    const int row = (bid & 7) * (BB * NN / 8) + (bid >> 3);  // bijective
    const int bb  = row >> 8;        // N = 256
    const int t   = threadIdx.x;     // 0..255

    __shared__ float sc[HEADS][260];
    __shared__ float qs[EMBED];
    __shared__ float msk[NN];

    if (t < EMBED) qs[t] = q[(size_t)row * EMBED + t];
    msk[t] = mask[(size_t)row * NN + t];
    __syncthreads();

    const int g = t >> 5;
    const int l = t & 31;
    float4 q4 = *reinterpret_cast<const float4*>(&qs[4 * l]);

    const size_t pe_row = (size_t)row * NN * EMBED;
    const size_t k_row  = (size_t)bb * NN * EMBED;
    const int rot = row & 31;

    #pragma unroll 8
    for (int jt0 = 0; jt0 < 32; ++jt0) {
        const int jt = (jt0 + rot) & 31;
        const int j  = jt * 8 + g;
        const floatx4 p4 = __builtin_nontemporal_load(
            reinterpret_cast<const floatx4*>(pe + pe_row + (size_t)j * EMBED + 4 * l));
        const float4 k4 = *reinterpret_cast<const float4*>(k + k_row + (size_t)j * EMBED + 4 * l);
        float s = q4.x * (k4.x + p4.x) + q4.y * (k4.y + p4.y)
                + q4.z * (k4.z + p4.z) + q4.w * (k4.w + p4.w);
        s += __shfl_xor(s, 1);
        s += __shfl_xor(s, 2);
        if ((l & 3) == 0) {
            sc[l >> 2][j] = s * 0.25f;
        }
    }
    __syncthreads();

    {
        float vals[8];
        float m = -1e30f;
        #pragma unroll
        for (int r = 0; r < 8; ++r) {
            vals[r] = sc[g][l + 32 * r] + msk[l + 32 * r];
            m = fmaxf(m, vals[r]);
        }
        #pragma unroll
        for (int off = 16; off >= 1; off >>= 1) m = fmaxf(m, __shfl_xor(m, off));
        float ssum = 0.f;
        #pragma unroll
        for (int r = 0; r < 8; ++r) { float e2 = __expf(vals[r] - m); vals[r] = e2; ssum += e2; }
        #pragma unroll
        for (int off = 16; off >= 1; off >>= 1) ssum += __shfl_xor(ssum, off);
        float inv = 1.0f / ssum;
        __hip_bfloat16* pout = probs + ((size_t)row * HEADS + g) * NN;
        #pragma unroll
        for (int r = 0; r < 8; ++r) pout[l + 32 * r] = __float2bfloat16(vals[r] * inv);
    }
}

// ---- Kernel C1: PV + Wo + residual + LN2 (4 rows/block, ~12 KB LDS) -------
__global__ __launch_bounds__(256) void pv_wo_ln2_kernel(
    const float* __restrict__ x,
    const __hip_bfloat16* __restrict__ probs,
    const float* __restrict__ v,
    const float* __restrict__ Wo, const float* __restrict__ bo,
    const float* __restrict__ ln2_g, const float* __restrict__ ln2_b,
    float* __restrict__ x2g, float* __restrict__ xn2g)
{
    const int blk  = blockIdx.x;         // 0..1023
    const int b    = blk >> 6;
    const int row0 = b * NN + ((blk & 63) << 2);
    const int t    = threadIdx.x;

    __shared__ float red4[4][4][EMBED];  // 8 KB
    __shared__ float ctx[4][EMBED];      // 2 KB
    __shared__ float x2s[4][EMBED];      // 2 KB

    const int e4  = t & 31;
    const int grp = t >> 5;

    // ---- P1: PV -----------------------------------------------------------
    {
        const int seg = grp;             // j in [32seg, 32seg+32)
        const int h   = e4 >> 2;
        floatx4 a0 = {0,0,0,0}, a1 = a0, a2 = a0, a3 = a0;
        const float* vb = v + ((size_t)(b * NN + seg * 32)) * EMBED + 4 * e4;
        const size_t p0o = ((size_t)(row0 + 0) * HEADS + h) * NN + seg * 32;
        const size_t p1o = ((size_t)(row0 + 1) * HEADS + h) * NN + seg * 32;
        const size_t p2o = ((size_t)(row0 + 2) * HEADS + h) * NN + seg * 32;
        const size_t p3o = ((size_t)(row0 + 3) * HEADS + h) * NN + seg * 32;
        #pragma unroll 4
        for (int jj = 0; jj < 32; ++jj) {
            const floatx4 v4 = *reinterpret_cast<const floatx4*>(vb + (size_t)jj * EMBED);
            const float p0 = __bfloat162float(probs[p0o + jj]);
            const float p1 = __bfloat162float(probs[p1o + jj]);
            const float p2 = __bfloat162float(probs[p2o + jj]);
            const float p3 = __bfloat162float(probs[p3o + jj]);
            a0 += p0 * v4; a1 += p1 * v4; a2 += p2 * v4; a3 += p3 * v4;
        }
        a0.x += __shfl_xor(a0.x, 32); a0.y += __shfl_xor(a0.y, 32);
        a0.z += __shfl_xor(a0.z, 32); a0.w += __shfl_xor(a0.w, 32);
        a1.x += __shfl_xor(a1.x, 32); a1.y += __shfl_xor(a1.y, 32);
        a1.z += __shfl_xor(a1.z, 32); a1.w += __shfl_xor(a1.w, 32);
        a2.x += __shfl_xor(a2.x, 32); a2.y += __shfl_xor(a2.y, 32);
        a2.z += __shfl_xor(a2.z, 32); a2.w += __shfl_xor(a2.w, 32);
        a3.x += __shfl_xor(a3.x, 32); a3.y += __shfl_xor(a3.y, 32);
        a3.z += __shfl_xor(a3.z, 32); a3.w += __shfl_xor(a3.w, 32);
        if ((t & 63) < 32) {
            const int w = t >> 6;
            *reinterpret_cast<floatx4*>(&red4[w][0][4 * e4]) = a0;
            *reinterpret_cast<floatx4*>(&red4[w][1][4 * e4]) = a1;
            *reinterpret_cast<floatx4*>(&red4[w][2][4 * e4]) = a2;
            *reinterpret_cast<floatx4*>(&red4[w][3][4 * e4]) = a3;
        }
    }
    __syncthreads();
    if (t < 128) {
        #pragma unroll
        for (int r = 0; r < 4; ++r)
            ctx[r][t] = red4[0][r][t] + red4[1][r][t] + red4[2][r][t] + red4[3][r][t];
    }
    __syncthreads();

    // ---- P2: Wo + residual -> x2s (LDS) + x2g (global) --------------------
    {
        const int e = t & 127, rp = t >> 7;
        float a0 = bo[e], a1 = bo[e];
        #pragma unroll 8
        for (int c = 0; c < EMBED; ++c) {
            const float w = Wo[c * EMBED + e];
            a0 += ctx[2 * rp][c] * w;
            a1 += ctx[2 * rp + 1][c] * w;
        }
        a0 += x[(size_t)(row0 + 2 * rp) * EMBED + e];
        a1 += x[(size_t)(row0 + 2 * rp + 1) * EMBED + e];
        x2s[2 * rp][e] = a0;
        x2s[2 * rp + 1][e] = a1;
        x2g[(size_t)(row0 + 2 * rp) * EMBED + e] = a0;
        x2g[(size_t)(row0 + 2 * rp + 1) * EMBED + e] = a1;
    }
    __syncthreads();

    // ---- P3: LN2 (wave butterfly per row) -> xn2g -------------------------
    {
        const int wid = t >> 6, l64 = t & 63;
        const float v0 = x2s[wid][l64], v1 = x2s[wid][l64 + 64];
        float s  = v0 + v1;
        float sq = v0 * v0 + v1 * v1;
        #pragma unroll
        for (int off = 32; off >= 1; off >>= 1) {
            s  += __shfl_xor(s, off);
            sq += __shfl_xor(sq, off);
        }
        const float mu  = s * (1.0f / EMBED);
        const float var = sq * (1.0f / EMBED) - mu * mu;
        const float rs  = rsqrtf(var + 1e-5f);
        xn2g[(size_t)(row0 + wid) * EMBED + l64] =
            (v0 - mu) * rs * ln2_g[l64] + ln2_b[l64];
        xn2g[(size_t)(row0 + wid) * EMBED + 64 + l64] =
            (v1 - mu) * rs * ln2_g[l64 + 64] + ln2_b[l64 + 64];
    }
}

// ---- Kernel C2: FFN + residual (8 rows/block, weights read once) ----------
__global__ __launch_bounds__(256) void ffn_kernel(
    const float* __restrict__ x2g,
    const float* __restrict__ xn2g,
    const float* __restrict__ W1, const float* __restrict__ b1,
    const float* __restrict__ W2, const float* __restrict__ b2,
    float* __restrict__ out)
{
    const int row0 = blockIdx.x * 8;     // 512 blocks
    const int t    = threadIdx.x;        // 0..255

    __shared__ float xn2s[8][EMBED];     // 4 KB
    __shared__ float hb[8][FFN];         // 16 KB

    // stage xn2 (8 rows = 1024 floats = 256 x float4, fully coalesced)
    {
        const floatx4 v4 = *reinterpret_cast<const floatx4*>(
            xn2g + (size_t)row0 * EMBED + 4 * t);
        *reinterpret_cast<floatx4*>(&xn2s[0][0] + 4 * t) = v4;
    }
    __syncthreads();

    // FFN1: thread t covers hidden cols t and t+256, all 8 rows
    {
        float h0[8], h1[8];
        const float c0 = b1[t], c1 = b1[t + 256];
        #pragma unroll
        for (int r = 0; r < 8; ++r) { h0[r] = c0; h1[r] = c1; }
        #pragma unroll 2
        for (int c = 0; c < EMBED; ++c) {
            const float w0 = W1[c * FFN + t];
            const float w1 = W1[c * FFN + t + 256];
            #pragma unroll
            for (int r = 0; r < 8; ++r) {
                const float xc = xn2s[r][c];
                h0[r] += xc * w0;
                h1[r] += xc * w1;
            }
        }
        #pragma unroll
        for (int r = 0; r < 8; ++r) {
            hb[r][t]       = fmaxf(h0[r], 0.f);
            hb[r][t + 256] = fmaxf(h1[r], 0.f);
        }
    }
    __syncthreads();

    // FFN2 + residual: thread (e = t&127, half = t>>7) -> 4 rows
    {
        const int e = t & 127, half = t >> 7;
        const int r0 = half * 4;
        float a0 = 0.f, a1 = 0.f, a2 = 0.f, a3 = 0.f;
        #pragma unroll 4
        for (int f = 0; f < FFN; ++f) {
            const float w = W2[f * EMBED + e];
            a0 += hb[r0 + 0][f] * w;
            a1 += hb[r0 + 1][f] * w;
            a2 += hb[r0 + 2][f] * w;
            a3 += hb[r0 + 3][f] * w;
        }
        const float bv_ = b2[e];
        out[(size_t)(row0 + r0 + 0) * EMBED + e] =
            x2g[(size_t)(row0 + r0 + 0) * EMBED + e] + bv_ + a0;
        out[(size_t)(row0 + r0 + 1) * EMBED + e] =
            x2g[(size_t)(row0 + r0 + 1) * EMBED + e] + bv_ + a1;
        out[(size_t)(row0 + r0 + 2) * EMBED + e] =
            x2g[(size_t)(row0 + r0 + 2) * EMBED + e] + bv_ + a2;
        out[(size_t)(row0 + r0 + 3) * EMBED + e] =
            x2g[(size_t)(row0 + r0 + 3) * EMBED + e] + bv_ + a3;
    }
}

extern "C" void kernel_launch(void* const* d_in, const int* in_sizes, int n_in,
                              void* d_out, int out_size, void* d_ws, size_t ws_size,
                              hipStream_t stream) {
    const float* x    = (const float*)d_in[0];
    const float* pe   = (const float*)d_in[1];
    const float* mask = (const float*)d_in[2];
    const float* ln1g = (const float*)d_in[3];
    const float* ln1b = (const float*)d_in[4];
    const float* Wq   = (const float*)d_in[5];
    const float* bq   = (const float*)d_in[6];
    const float* Wk   = (const float*)d_in[7];
    const float* bk   = (const float*)d_in[8];
    const float* Wv   = (const float*)d_in[9];
    const float* bv   = (const float*)d_in[10];
    const float* Wo   = (const float*)d_in[11];
    const float* bo   = (const float*)d_in[12];
    const float* ln2g = (const float*)d_in[13];
    const float* ln2b = (const float*)d_in[14];
    const float* W1   = (const float*)d_in[15];
    const float* b1   = (const float*)d_in[16];
    const float* W2   = (const float*)d_in[17];
    const float* b2   = (const float*)d_in[18];
    float* out = (float*)d_out;

    float* q    = (float*)d_ws;
    float* kk   = q    + (size_t)BB * NN * EMBED;
    float* vv   = kk   + (size_t)BB * NN * EMBED;
    float* x2g  = vv   + (size_t)BB * NN * EMBED;
    float* xn2g = x2g  + (size_t)BB * NN * EMBED;
    __hip_bfloat16* probs = (__hip_bfloat16*)(xn2g + (size_t)BB * NN * EMBED);

    ln1_qkv_kernel<<<BB * NN / 8, 128, 0, stream>>>(x, ln1g, ln1b, Wq, bq, Wk, bk, Wv, bv, q, kk, vv);
    scores_softmax_kernel<<<BB * NN, 256, 0, stream>>>(pe, mask, q, kk, probs);
    pv_wo_ln2_kernel<<<BB * NN / 4, 256, 0, stream>>>(x, probs, vv, Wo, bo,
                                                      ln2g, ln2b, x2g, xn2g);
    ffn_kernel<<<BB * NN / 8, 256, 0, stream>>>(x2g, xn2g, W1, b1, W2, b2, out);
}

// Round 11
// 200.893 us; speedup vs baseline: 1.1817x; 1.0056x over previous
//
#include <hip/hip_runtime.h>
#include <hip/hip_bf16.h>

#define EMBED 128
#define HEADS 8
#define DH 16
#define FFN 512
#define BB 16
#define NN 256

typedef float floatx4 __attribute__((ext_vector_type(4)));

// ---- Kernel A: LN1 + QKV, 8 rows/block (weights read once per 8 rows) -----
__global__ __launch_bounds__(128) void ln1_qkv_kernel(
    const float* __restrict__ x,
    const float* __restrict__ ln1_g, const float* __restrict__ ln1_b,
    const float* __restrict__ Wq, const float* __restrict__ bq,
    const float* __restrict__ Wk, const float* __restrict__ bk,
    const float* __restrict__ Wv, const float* __restrict__ bv,
    float* __restrict__ q, float* __restrict__ k, float* __restrict__ v)
{
    const int row0 = blockIdx.x * 8;     // 512 blocks
    const int t    = threadIdx.x;        // 0..127
    const int wv_  = t >> 6;             // wave 0..1
    const int l64  = t & 63;

    __shared__ float xn[8][EMBED];

    #pragma unroll
    for (int rr = 0; rr < 4; ++rr) {
        const int r = wv_ * 4 + rr;
        const float v0 = x[(size_t)(row0 + r) * EMBED + l64];
        const float v1 = x[(size_t)(row0 + r) * EMBED + 64 + l64];
        float s  = v0 + v1;
        float sq = v0 * v0 + v1 * v1;
        #pragma unroll
        for (int off = 32; off >= 1; off >>= 1) {
            s  += __shfl_xor(s, off);
            sq += __shfl_xor(sq, off);
        }
        const float mu  = s * (1.0f / EMBED);
        const float var = sq * (1.0f / EMBED) - mu * mu;
        const float rs  = rsqrtf(var + 1e-5f);
        xn[r][l64]      = (v0 - mu) * rs * ln1_g[l64]      + ln1_b[l64];
        xn[r][l64 + 64] = (v1 - mu) * rs * ln1_g[l64 + 64] + ln1_b[l64 + 64];
    }
    __syncthreads();

    const int e = t;
    float aq[8], ak[8], av[8];
    const float bqe = bq[e], bke = bk[e], bve = bv[e];
    #pragma unroll
    for (int r = 0; r < 8; ++r) { aq[r] = bqe; ak[r] = bke; av[r] = bve; }

    #pragma unroll 4
    for (int c = 0; c < EMBED; ++c) {
        const float wq = Wq[c * EMBED + e];
        const float wk = Wk[c * EMBED + e];
        const float wv2 = Wv[c * EMBED + e];
        #pragma unroll
        for (int r = 0; r < 8; ++r) {
            const float xc = xn[r][c];
            aq[r] += xc * wq;
            ak[r] += xc * wk;
            av[r] += xc * wv2;
        }
    }
    #pragma unroll
    for (int r = 0; r < 8; ++r) {
        const size_t o = (size_t)(row0 + r) * EMBED + e;
        q[o] = aq[r]; k[o] = ak[r]; v[o] = av[r];
    }
}

// ---- Kernel B: scores + softmax + PV + Wo + residual + LN2 (fused) --------
// Streaming phase identical to R7 (rotation + XCD swizzle, ~4.3 TB/s read
// ceiling). Tail phases consume LDS probs + L2-resident v/Wo/x, overlapping
// with other blocks' streaming.
__global__ __launch_bounds__(256) void scores_pv_kernel(
    const float* __restrict__ pe,
    const float* __restrict__ mask,
    const float* __restrict__ q, const float* __restrict__ k,
    const float* __restrict__ v,
    const float* __restrict__ x,
    const float* __restrict__ Wo, const float* __restrict__ bo,
    const float* __restrict__ ln2_g, const float* __restrict__ ln2_b,
    float* __restrict__ x2g, float* __restrict__ xn2g)
{
    const int bid = blockIdx.x;
    const int row = (bid & 7) * (BB * NN / 8) + (bid >> 3);  // bijective
    const int bb  = row >> 8;        // N = 256
    const int t   = threadIdx.x;     // 0..255

    __shared__ float sc[HEADS][260];   // scores -> probs (fp32)
    __shared__ float qs[EMBED];        // q fragment; reused as ctx later
    __shared__ float msk[NN];
    __shared__ float red4[4][EMBED];   // PV wave partials
    __shared__ float wred[2][EMBED];   // Wo c-half partials
    __shared__ float x2s[EMBED];

    if (t < EMBED) qs[t] = q[(size_t)row * EMBED + t];
    msk[t] = mask[(size_t)row * NN + t];
    __syncthreads();

    const int g = t >> 5;
    const int l = t & 31;
    float4 q4 = *reinterpret_cast<const float4*>(&qs[4 * l]);

    const size_t pe_row = (size_t)row * NN * EMBED;
    const size_t k_row  = (size_t)bb * NN * EMBED;
    const int rot = row & 31;

    // ---- P1: stream pe (+ L2 k), scores into LDS --------------------------
    #pragma unroll 8
    for (int jt0 = 0; jt0 < 32; ++jt0) {
        const int jt = (jt0 + rot) & 31;
        const int j  = jt * 8 + g;
        const floatx4 p4 = __builtin_nontemporal_load(
            reinterpret_cast<const floatx4*>(pe + pe_row + (size_t)j * EMBED + 4 * l));
        const float4 k4 = *reinterpret_cast<const float4*>(k + k_row + (size_t)j * EMBED + 4 * l);
        float s = q4.x * (k4.x + p4.x) + q4.y * (k4.y + p4.y)
                + q4.z * (k4.z + p4.z) + q4.w * (k4.w + p4.w);
        s += __shfl_xor(s, 1);
        s += __shfl_xor(s, 2);
        if ((l & 3) == 0) {
            sc[l >> 2][j] = s * 0.25f;
        }
    }
    __syncthreads();

    // ---- P2: softmax per head; write normalized probs back to sc ---------
    {
        float vals[8];
        float m = -1e30f;
        #pragma unroll
        for (int r = 0; r < 8; ++r) {
            vals[r] = sc[g][l + 32 * r] + msk[l + 32 * r];
            m = fmaxf(m, vals[r]);
        }
        #pragma unroll
        for (int off = 16; off >= 1; off >>= 1) m = fmaxf(m, __shfl_xor(m, off));
        float ssum = 0.f;
        #pragma unroll
        for (int r = 0; r < 8; ++r) { float e2 = __expf(vals[r] - m); vals[r] = e2; ssum += e2; }
        #pragma unroll
        for (int off = 16; off >= 1; off >>= 1) ssum += __shfl_xor(ssum, off);
        float inv = 1.0f / ssum;
        #pragma unroll
        for (int r = 0; r < 8; ++r) sc[g][l + 32 * r] = vals[r] * inv;
    }
    __syncthreads();

    // ---- P3: PV. thread (e4 = t&31, seg = t>>5): 32 j per seg -------------
    {
        const int e4  = t & 31;
        const int seg = t >> 5;
        const int h   = e4 >> 2;
        floatx4 acc = {0, 0, 0, 0};
        const float* vb = v + ((size_t)(bb * NN + seg * 32)) * EMBED + 4 * e4;
        const float* pr = &sc[h][seg * 32];
        #pragma unroll 4
        for (int jj = 0; jj < 32; ++jj) {
            const floatx4 v4 = *reinterpret_cast<const floatx4*>(vb + (size_t)jj * EMBED);
            acc += pr[jj] * v4;
        }
        acc.x += __shfl_xor(acc.x, 32); acc.y += __shfl_xor(acc.y, 32);
        acc.z += __shfl_xor(acc.z, 32); acc.w += __shfl_xor(acc.w, 32);
        if ((t & 63) < 32) {
            *reinterpret_cast<floatx4*>(&red4[t >> 6][4 * e4]) = acc;
        }
    }
    __syncthreads();
    if (t < 128) {
        qs[t] = red4[0][t] + red4[1][t] + red4[2][t] + red4[3][t];  // ctx
    }
    __syncthreads();

    // ---- P4: Wo (c-half per rp) -------------------------------------------
    {
        const int e = t & 127, rp = t >> 7;
        float a = 0.f;
        const float* Wob = Wo + rp * 64 * EMBED + e;
        #pragma unroll 8
        for (int cc = 0; cc < 64; ++cc) {
            a += qs[rp * 64 + cc] * Wob[cc * EMBED];
        }
        wred[rp][e] = a;
    }
    __syncthreads();

    // ---- P5: combine + bias + residual -> x2 ------------------------------
    if (t < 128) {
        const float a2 = wred[0][t] + wred[1][t] + bo[t]
                       + x[(size_t)row * EMBED + t];
        x2s[t] = a2;
        x2g[(size_t)row * EMBED + t] = a2;
    }
    __syncthreads();

    // ---- P6: LN2 (wave-0 butterfly) -> xn2g -------------------------------
    if (t < 64) {
        const float v0 = x2s[t], v1 = x2s[t + 64];
        float s  = v0 + v1;
        float sq = v0 * v0 + v1 * v1;
        #pragma unroll
        for (int off = 32; off >= 1; off >>= 1) {
            s  += __shfl_xor(s, off);
            sq += __shfl_xor(sq, off);
        }
        const float mu  = s * (1.0f / EMBED);
        const float var = sq * (1.0f / EMBED) - mu * mu;
        const float rs  = rsqrtf(var + 1e-5f);
        xn2g[(size_t)row * EMBED + t] =
            (v0 - mu) * rs * ln2_g[t] + ln2_b[t];
        xn2g[(size_t)row * EMBED + 64 + t] =
            (v1 - mu) * rs * ln2_g[t + 64] + ln2_b[t + 64];
    }
}

// ---- Kernel C2: FFN + residual (8 rows/block, weights read once) ----------
__global__ __launch_bounds__(256) void ffn_kernel(
    const float* __restrict__ x2g,
    const float* __restrict__ xn2g,
    const float* __restrict__ W1, const float* __restrict__ b1,
    const float* __restrict__ W2, const float* __restrict__ b2,
    float* __restrict__ out)
{
    const int row0 = blockIdx.x * 8;     // 512 blocks
    const int t    = threadIdx.x;        // 0..255

    __shared__ float xn2s[8][EMBED];     // 4 KB
    __shared__ float hb[8][FFN];         // 16 KB

    {
        const floatx4 v4 = *reinterpret_cast<const floatx4*>(
            xn2g + (size_t)row0 * EMBED + 4 * t);
        *reinterpret_cast<floatx4*>(&xn2s[0][0] + 4 * t) = v4;
    }
    __syncthreads();

    {
        float h0[8], h1[8];
        const float c0 = b1[t], c1 = b1[t + 256];
        #pragma unroll
        for (int r = 0; r < 8; ++r) { h0[r] = c0; h1[r] = c1; }
        #pragma unroll 2
        for (int c = 0; c < EMBED; ++c) {
            const float w0 = W1[c * FFN + t];
            const float w1 = W1[c * FFN + t + 256];
            #pragma unroll
            for (int r = 0; r < 8; ++r) {
                const float xc = xn2s[r][c];
                h0[r] += xc * w0;
                h1[r] += xc * w1;
            }
        }
        #pragma unroll
        for (int r = 0; r < 8; ++r) {
            hb[r][t]       = fmaxf(h0[r], 0.f);
            hb[r][t + 256] = fmaxf(h1[r], 0.f);
        }
    }
    __syncthreads();

    {
        const int e = t & 127, half = t >> 7;
        const int r0 = half * 4;
        float a0 = 0.f, a1 = 0.f, a2 = 0.f, a3 = 0.f;
        #pragma unroll 4
        for (int f = 0; f < FFN; ++f) {
            const float w = W2[f * EMBED + e];
            a0 += hb[r0 + 0][f] * w;
            a1 += hb[r0 + 1][f] * w;
            a2 += hb[r0 + 2][f] * w;
            a3 += hb[r0 + 3][f] * w;
        }
        const float bv_ = b2[e];
        out[(size_t)(row0 + r0 + 0) * EMBED + e] =
            x2g[(size_t)(row0 + r0 + 0) * EMBED + e] + bv_ + a0;
        out[(size_t)(row0 + r0 + 1) * EMBED + e] =
            x2g[(size_t)(row0 + r0 + 1) * EMBED + e] + bv_ + a1;
        out[(size_t)(row0 + r0 + 2) * EMBED + e] =
            x2g[(size_t)(row0 + r0 + 2) * EMBED + e] + bv_ + a2;
        out[(size_t)(row0 + r0 + 3) * EMBED + e] =
            x2g[(size_t)(row0 + r0 + 3) * EMBED + e] + bv_ + a3;
    }
}

extern "C" void kernel_launch(void* const* d_in, const int* in_sizes, int n_in,
                              void* d_out, int out_size, void* d_ws, size_t ws_size,
                              hipStream_t stream) {
    const float* x    = (const float*)d_in[0];
    const float* pe   = (const float*)d_in[1];
    const float* mask = (const float*)d_in[2];
    const float* ln1g = (const float*)d_in[3];
    const float* ln1b = (const float*)d_in[4];
    const float* Wq   = (const float*)d_in[5];
    const float* bq   = (const float*)d_in[6];
    const float* Wk   = (const float*)d_in[7];
    const float* bk   = (const float*)d_in[8];
    const float* Wv   = (const float*)d_in[9];
    const float* bv   = (const float*)d_in[10];
    const float* Wo   = (const float*)d_in[11];
    const float* bo   = (const float*)d_in[12];
    const float* ln2g = (const float*)d_in[13];
    const float* ln2b = (const float*)d_in[14];
    const float* W1   = (const float*)d_in[15];
    const float* b1   = (const float*)d_in[16];
    const float* W2   = (const float*)d_in[17];
    const float* b2   = (const float*)d_in[18];
    float* out = (float*)d_out;

    float* q    = (float*)d_ws;
    float* kk   = q    + (size_t)BB * NN * EMBED;
    float* vv   = kk   + (size_t)BB * NN * EMBED;
    float* x2g  = vv   + (size_t)BB * NN * EMBED;
    float* xn2g = x2g  + (size_t)BB * NN * EMBED;

    ln1_qkv_kernel<<<BB * NN / 8, 128, 0, stream>>>(x, ln1g, ln1b, Wq, bq, Wk, bk, Wv, bv, q, kk, vv);
    scores_pv_kernel<<<BB * NN, 256, 0, stream>>>(pe, mask, q, kk, vv, x, Wo, bo,
                                                  ln2g, ln2b, x2g, xn2g);
    ffn_kernel<<<BB * NN / 8, 256, 0, stream>>>(x2g, xn2g, W1, b1, W2, b2, out);
}

// Round 12
// 178.946 us; speedup vs baseline: 1.3267x; 1.1226x over previous
//
#include <hip/hip_runtime.h>
#include <hip/hip_bf16.h>
#include <hip/hip_fp16.h>

#define EMBED 128
#define HEADS 8
#define DH 16
#define FFN 512
#define BB 16
#define NN 256

typedef float floatx4 __attribute__((ext_vector_type(4)));

// ---- Kernel A: LN1 + QKV, 8 rows/block (weights read once per 8 rows) -----
__global__ __launch_bounds__(128) void ln1_qkv_kernel(
    const float* __restrict__ x,
    const float* __restrict__ ln1_g, const float* __restrict__ ln1_b,
    const float* __restrict__ Wq, const float* __restrict__ bq,
    const float* __restrict__ Wk, const float* __restrict__ bk,
    const float* __restrict__ Wv, const float* __restrict__ bv,
    float* __restrict__ q, float* __restrict__ k, float* __restrict__ v)
{
    const int row0 = blockIdx.x * 8;     // 512 blocks
    const int t    = threadIdx.x;        // 0..127
    const int wv_  = t >> 6;             // wave 0..1
    const int l64  = t & 63;

    __shared__ float xn[8][EMBED];

    #pragma unroll
    for (int rr = 0; rr < 4; ++rr) {
        const int r = wv_ * 4 + rr;
        const float v0 = x[(size_t)(row0 + r) * EMBED + l64];
        const float v1 = x[(size_t)(row0 + r) * EMBED + 64 + l64];
        float s  = v0 + v1;
        float sq = v0 * v0 + v1 * v1;
        #pragma unroll
        for (int off = 32; off >= 1; off >>= 1) {
            s  += __shfl_xor(s, off);
            sq += __shfl_xor(sq, off);
        }
        const float mu  = s * (1.0f / EMBED);
        const float var = sq * (1.0f / EMBED) - mu * mu;
        const float rs  = rsqrtf(var + 1e-5f);
        xn[r][l64]      = (v0 - mu) * rs * ln1_g[l64]      + ln1_b[l64];
        xn[r][l64 + 64] = (v1 - mu) * rs * ln1_g[l64 + 64] + ln1_b[l64 + 64];
    }
    __syncthreads();

    const int e = t;
    float aq[8], ak[8], av[8];
    const float bqe = bq[e], bke = bk[e], bve = bv[e];
    #pragma unroll
    for (int r = 0; r < 8; ++r) { aq[r] = bqe; ak[r] = bke; av[r] = bve; }

    #pragma unroll 4
    for (int c = 0; c < EMBED; ++c) {
        const float wq = Wq[c * EMBED + e];
        const float wk = Wk[c * EMBED + e];
        const float wv2 = Wv[c * EMBED + e];
        #pragma unroll
        for (int r = 0; r < 8; ++r) {
            const float xc = xn[r][c];
            aq[r] += xc * wq;
            ak[r] += xc * wk;
            av[r] += xc * wv2;
        }
    }
    #pragma unroll
    for (int r = 0; r < 8; ++r) {
        const size_t o = (size_t)(row0 + r) * EMBED + e;
        q[o] = aq[r]; k[o] = ak[r]; v[o] = av[r];
    }
}

// ---- Kernel B: 4 rows/block: stream + softmax + PV + Wo + res + LN2 -------
// k loaded once per j (reused x4 rows in regs); v/Wo L2 reads amortized x4.
// Scores/probs in fp16 LDS to keep 4 blocks/CU.
__global__ __launch_bounds__(256) void scores_pv_kernel(
    const float* __restrict__ pe,
    const float* __restrict__ mask,
    const float* __restrict__ q, const float* __restrict__ k,
    const float* __restrict__ v,
    const float* __restrict__ x,
    const float* __restrict__ Wo, const float* __restrict__ bo,
    const float* __restrict__ ln2_g, const float* __restrict__ ln2_b,
    float* __restrict__ x2g, float* __restrict__ xn2g)
{
    const int bid  = blockIdx.x;                    // 0..1023
    const int blk  = (bid & 7) * 128 + (bid >> 3);  // XCD-chunked, bijective
    const int row0 = blk * 4;
    const int bb   = row0 >> 8;
    const int t    = threadIdx.x;                   // 0..255

    __shared__ __half sc[4][HEADS][264];   // 16.9 KB scores->probs
    __shared__ float red4[4][4][EMBED];    // 8 KB PV wave partials
    __shared__ float ctx[4][EMBED];        // 2 KB
    __shared__ float wred[2][4][EMBED];    // 4 KB Wo c-half partials
    __shared__ float x2s[4][EMBED];        // 2 KB

    const int g = t >> 5;            // 0..7
    const int l = t & 31;            // lane covers dims 4l..4l+3

    // q fragments for 4 rows (broadcast-friendly loads)
    floatx4 q4[4];
    #pragma unroll
    for (int r = 0; r < 4; ++r)
        q4[r] = *reinterpret_cast<const floatx4*>(q + (size_t)(row0 + r) * EMBED + 4 * l);

    const size_t pe_base = (size_t)row0 * NN * EMBED;
    const size_t k_row   = (size_t)bb * NN * EMBED;
    const int rot = blk & 31;

    // ---- P1: stream pe for 4 rows; k loaded once per j --------------------
    #pragma unroll 4
    for (int jt0 = 0; jt0 < 32; ++jt0) {
        const int jt = (jt0 + rot) & 31;
        const int j  = jt * 8 + g;
        const floatx4 k4 = *reinterpret_cast<const floatx4*>(k + k_row + (size_t)j * EMBED + 4 * l);
        #pragma unroll
        for (int r = 0; r < 4; ++r) {
            const floatx4 p4 = __builtin_nontemporal_load(
                reinterpret_cast<const floatx4*>(pe + pe_base + ((size_t)r * NN + j) * EMBED + 4 * l));
            const floatx4 sum = k4 + p4;
            float s = q4[r].x * sum.x + q4[r].y * sum.y + q4[r].z * sum.z + q4[r].w * sum.w;
            s += __shfl_xor(s, 1);
            s += __shfl_xor(s, 2);
            if ((l & 3) == 0) sc[r][l >> 2][j] = __float2half(s * 0.25f);
        }
    }
    __syncthreads();

    // ---- P2: softmax; group g = head g, loop rows; probs back to sc ------
    #pragma unroll
    for (int r = 0; r < 4; ++r) {
        const float* mrow = mask + (size_t)(row0 + r) * NN;
        float vals[8];
        float m = -1e30f;
        #pragma unroll
        for (int rr = 0; rr < 8; ++rr) {
            vals[rr] = __half2float(sc[r][g][l + 32 * rr]) + mrow[l + 32 * rr];
            m = fmaxf(m, vals[rr]);
        }
        #pragma unroll
        for (int off = 16; off >= 1; off >>= 1) m = fmaxf(m, __shfl_xor(m, off));
        float ssum = 0.f;
        #pragma unroll
        for (int rr = 0; rr < 8; ++rr) { float e2 = __expf(vals[rr] - m); vals[rr] = e2; ssum += e2; }
        #pragma unroll
        for (int off = 16; off >= 1; off >>= 1) ssum += __shfl_xor(ssum, off);
        const float inv = 1.0f / ssum;
        #pragma unroll
        for (int rr = 0; rr < 8; ++rr) sc[r][g][l + 32 * rr] = __float2half(vals[rr] * inv);
    }
    __syncthreads();

    // ---- P3: PV. thread (e4, seg): v loaded once, reused x4 rows ----------
    {
        const int e4  = t & 31;
        const int seg = t >> 5;
        const int h   = e4 >> 2;
        floatx4 acc0 = {0,0,0,0}, acc1 = acc0, acc2 = acc0, acc3 = acc0;
        const float* vb = v + ((size_t)(bb * NN + seg * 32)) * EMBED + 4 * e4;
        #pragma unroll 4
        for (int jj = 0; jj < 32; ++jj) {
            const floatx4 v4 = *reinterpret_cast<const floatx4*>(vb + (size_t)jj * EMBED);
            acc0 += __half2float(sc[0][h][seg * 32 + jj]) * v4;
            acc1 += __half2float(sc[1][h][seg * 32 + jj]) * v4;
            acc2 += __half2float(sc[2][h][seg * 32 + jj]) * v4;
            acc3 += __half2float(sc[3][h][seg * 32 + jj]) * v4;
        }
        acc0.x += __shfl_xor(acc0.x, 32); acc0.y += __shfl_xor(acc0.y, 32);
        acc0.z += __shfl_xor(acc0.z, 32); acc0.w += __shfl_xor(acc0.w, 32);
        acc1.x += __shfl_xor(acc1.x, 32); acc1.y += __shfl_xor(acc1.y, 32);
        acc1.z += __shfl_xor(acc1.z, 32); acc1.w += __shfl_xor(acc1.w, 32);
        acc2.x += __shfl_xor(acc2.x, 32); acc2.y += __shfl_xor(acc2.y, 32);
        acc2.z += __shfl_xor(acc2.z, 32); acc2.w += __shfl_xor(acc2.w, 32);
        acc3.x += __shfl_xor(acc3.x, 32); acc3.y += __shfl_xor(acc3.y, 32);
        acc3.z += __shfl_xor(acc3.z, 32); acc3.w += __shfl_xor(acc3.w, 32);
        if ((t & 63) < 32) {
            const int w = t >> 6;
            *reinterpret_cast<floatx4*>(&red4[w][0][4 * e4]) = acc0;
            *reinterpret_cast<floatx4*>(&red4[w][1][4 * e4]) = acc1;
            *reinterpret_cast<floatx4*>(&red4[w][2][4 * e4]) = acc2;
            *reinterpret_cast<floatx4*>(&red4[w][3][4 * e4]) = acc3;
        }
    }
    __syncthreads();
    {
        #pragma unroll
        for (int rr = 0; rr < 2; ++rr) {
            const int idx = t + 256 * rr;      // 0..511 = r*128 + e
            const int r = idx >> 7, e = idx & 127;
            ctx[r][e] = red4[0][r][e] + red4[1][r][e] + red4[2][r][e] + red4[3][r][e];
        }
    }
    __syncthreads();

    // ---- P4: Wo. thread (e, rp = c-half); Wo element reused x4 rows -------
    {
        const int e = t & 127, rp = t >> 7;
        float a0 = 0.f, a1 = 0.f, a2 = 0.f, a3 = 0.f;
        const float* Wob = Wo + rp * 64 * EMBED + e;
        #pragma unroll 8
        for (int cc = 0; cc < 64; ++cc) {
            const float w = Wob[(size_t)cc * EMBED];
            a0 += ctx[0][rp * 64 + cc] * w;
            a1 += ctx[1][rp * 64 + cc] * w;
            a2 += ctx[2][rp * 64 + cc] * w;
            a3 += ctx[3][rp * 64 + cc] * w;
        }
        wred[rp][0][e] = a0; wred[rp][1][e] = a1;
        wred[rp][2][e] = a2; wred[rp][3][e] = a3;
    }
    __syncthreads();

    // ---- P5: combine + bias + residual -> x2 ------------------------------
    {
        #pragma unroll
        for (int rr = 0; rr < 2; ++rr) {
            const int idx = t + 256 * rr;
            const int r = idx >> 7, e = idx & 127;
            const float a2 = wred[0][r][e] + wred[1][r][e] + bo[e]
                           + x[(size_t)(row0 + r) * EMBED + e];
            x2s[r][e] = a2;
            x2g[(size_t)(row0 + r) * EMBED + e] = a2;
        }
    }
    __syncthreads();

    // ---- P6: LN2. wave w handles row w -------------------------------------
    {
        const int wid = t >> 6, l64 = t & 63;
        const float v0 = x2s[wid][l64], v1 = x2s[wid][l64 + 64];
        float s  = v0 + v1;
        float sq = v0 * v0 + v1 * v1;
        #pragma unroll
        for (int off = 32; off >= 1; off >>= 1) {
            s  += __shfl_xor(s, off);
            sq += __shfl_xor(sq, off);
        }
        const float mu  = s * (1.0f / EMBED);
        const float var = sq * (1.0f / EMBED) - mu * mu;
        const float rs  = rsqrtf(var + 1e-5f);
        xn2g[(size_t)(row0 + wid) * EMBED + l64] =
            (v0 - mu) * rs * ln2_g[l64] + ln2_b[l64];
        xn2g[(size_t)(row0 + wid) * EMBED + 64 + l64] =
            (v1 - mu) * rs * ln2_g[l64 + 64] + ln2_b[l64 + 64];
    }
}

// ---- Kernel C2: FFN + residual (8 rows/block, weights read once) ----------
__global__ __launch_bounds__(256) void ffn_kernel(
    const float* __restrict__ x2g,
    const float* __restrict__ xn2g,
    const float* __restrict__ W1, const float* __restrict__ b1,
    const float* __restrict__ W2, const float* __restrict__ b2,
    float* __restrict__ out)
{
    const int row0 = blockIdx.x * 8;     // 512 blocks
    const int t    = threadIdx.x;        // 0..255

    __shared__ float xn2s[8][EMBED];     // 4 KB
    __shared__ float hb[8][FFN];         // 16 KB

    {
        const floatx4 v4 = *reinterpret_cast<const floatx4*>(
            xn2g + (size_t)row0 * EMBED + 4 * t);
        *reinterpret_cast<floatx4*>(&xn2s[0][0] + 4 * t) = v4;
    }
    __syncthreads();

    {
        float h0[8], h1[8];
        const float c0 = b1[t], c1 = b1[t + 256];
        #pragma unroll
        for (int r = 0; r < 8; ++r) { h0[r] = c0; h1[r] = c1; }
        #pragma unroll 2
        for (int c = 0; c < EMBED; ++c) {
            const float w0 = W1[c * FFN + t];
            const float w1 = W1[c * FFN + t + 256];
            #pragma unroll
            for (int r = 0; r < 8; ++r) {
                const float xc = xn2s[r][c];
                h0[r] += xc * w0;
                h1[r] += xc * w1;
            }
        }
        #pragma unroll
        for (int r = 0; r < 8; ++r) {
            hb[r][t]       = fmaxf(h0[r], 0.f);
            hb[r][t + 256] = fmaxf(h1[r], 0.f);
        }
    }
    __syncthreads();

    {
        const int e = t & 127, half = t >> 7;
        const int r0 = half * 4;
        float a0 = 0.f, a1 = 0.f, a2 = 0.f, a3 = 0.f;
        #pragma unroll 4
        for (int f = 0; f < FFN; ++f) {
            const float w = W2[f * EMBED + e];
            a0 += hb[r0 + 0][f] * w;
            a1 += hb[r0 + 1][f] * w;
            a2 += hb[r0 + 2][f] * w;
            a3 += hb[r0 + 3][f] * w;
        }
        const float bv_ = b2[e];
        out[(size_t)(row0 + r0 + 0) * EMBED + e] =
            x2g[(size_t)(row0 + r0 + 0) * EMBED + e] + bv_ + a0;
        out[(size_t)(row0 + r0 + 1) * EMBED + e] =
            x2g[(size_t)(row0 + r0 + 1) * EMBED + e] + bv_ + a1;
        out[(size_t)(row0 + r0 + 2) * EMBED + e] =
            x2g[(size_t)(row0 + r0 + 2) * EMBED + e] + bv_ + a2;
        out[(size_t)(row0 + r0 + 3) * EMBED + e] =
            x2g[(size_t)(row0 + r0 + 3) * EMBED + e] + bv_ + a3;
    }
}

extern "C" void kernel_launch(void* const* d_in, const int* in_sizes, int n_in,
                              void* d_out, int out_size, void* d_ws, size_t ws_size,
                              hipStream_t stream) {
    const float* x    = (const float*)d_in[0];
    const float* pe   = (const float*)d_in[1];
    const float* mask = (const float*)d_in[2];
    const float* ln1g = (const float*)d_in[3];
    const float* ln1b = (const float*)d_in[4];
    const float* Wq   = (const float*)d_in[5];
    const float* bq   = (const float*)d_in[6];
    const float* Wk   = (const float*)d_in[7];
    const float* bk   = (const float*)d_in[8];
    const float* Wv   = (const float*)d_in[9];
    const float* bv   = (const float*)d_in[10];
    const float* Wo   = (const float*)d_in[11];
    const float* bo   = (const float*)d_in[12];
    const float* ln2g = (const float*)d_in[13];
    const float* ln2b = (const float*)d_in[14];
    const float* W1   = (const float*)d_in[15];
    const float* b1   = (const float*)d_in[16];
    const float* W2   = (const float*)d_in[17];
    const float* b2   = (const float*)d_in[18];
    float* out = (float*)d_out;

    float* q    = (float*)d_ws;
    float* kk   = q    + (size_t)BB * NN * EMBED;
    float* vv   = kk   + (size_t)BB * NN * EMBED;
    float* x2g  = vv   + (size_t)BB * NN * EMBED;
    float* xn2g = x2g  + (size_t)BB * NN * EMBED;

    ln1_qkv_kernel<<<BB * NN / 8, 128, 0, stream>>>(x, ln1g, ln1b, Wq, bq, Wk, bk, Wv, bv, q, kk, vv);
    scores_pv_kernel<<<BB * NN / 4, 256, 0, stream>>>(pe, mask, q, kk, vv, x, Wo, bo,
                                                      ln2g, ln2b, x2g, xn2g);
    ffn_kernel<<<BB * NN / 8, 256, 0, stream>>>(x2g, xn2g, W1, b1, W2, b2, out);
}

// Round 13
// 156.417 us; speedup vs baseline: 1.5178x; 1.1440x over previous
//
#include <hip/hip_runtime.h>
#include <hip/hip_bf16.h>
#include <hip/hip_fp16.h>

#define EMBED 128
#define HEADS 8
#define DH 16
#define FFN 512
#define BB 16
#define NN 256

typedef float floatx4 __attribute__((ext_vector_type(4)));

// ---- Kernel A: LN1 + QKV, 8 rows/block (weights read once per 8 rows) -----
__global__ __launch_bounds__(128) void ln1_qkv_kernel(
    const float* __restrict__ x,
    const float* __restrict__ ln1_g, const float* __restrict__ ln1_b,
    const float* __restrict__ Wq, const float* __restrict__ bq,
    const float* __restrict__ Wk, const float* __restrict__ bk,
    const float* __restrict__ Wv, const float* __restrict__ bv,
    float* __restrict__ q, float* __restrict__ k, float* __restrict__ v)
{
    const int row0 = blockIdx.x * 8;     // 512 blocks
    const int t    = threadIdx.x;        // 0..127
    const int wv_  = t >> 6;             // wave 0..1
    const int l64  = t & 63;

    __shared__ float xn[8][EMBED];

    #pragma unroll
    for (int rr = 0; rr < 4; ++rr) {
        const int r = wv_ * 4 + rr;
        const float v0 = x[(size_t)(row0 + r) * EMBED + l64];
        const float v1 = x[(size_t)(row0 + r) * EMBED + 64 + l64];
        float s  = v0 + v1;
        float sq = v0 * v0 + v1 * v1;
        #pragma unroll
        for (int off = 32; off >= 1; off >>= 1) {
            s  += __shfl_xor(s, off);
            sq += __shfl_xor(sq, off);
        }
        const float mu  = s * (1.0f / EMBED);
        const float var = sq * (1.0f / EMBED) - mu * mu;
        const float rs  = rsqrtf(var + 1e-5f);
        xn[r][l64]      = (v0 - mu) * rs * ln1_g[l64]      + ln1_b[l64];
        xn[r][l64 + 64] = (v1 - mu) * rs * ln1_g[l64 + 64] + ln1_b[l64 + 64];
    }
    __syncthreads();

    const int e = t;
    float aq[8], ak[8], av[8];
    const float bqe = bq[e], bke = bk[e], bve = bv[e];
    #pragma unroll
    for (int r = 0; r < 8; ++r) { aq[r] = bqe; ak[r] = bke; av[r] = bve; }

    #pragma unroll 4
    for (int c = 0; c < EMBED; ++c) {
        const float wq = Wq[c * EMBED + e];
        const float wk = Wk[c * EMBED + e];
        const float wv2 = Wv[c * EMBED + e];
        #pragma unroll
        for (int r = 0; r < 8; ++r) {
            const float xc = xn[r][c];
            aq[r] += xc * wq;
            ak[r] += xc * wk;
            av[r] += xc * wv2;
        }
    }
    #pragma unroll
    for (int r = 0; r < 8; ++r) {
        const size_t o = (size_t)(row0 + r) * EMBED + e;
        q[o] = aq[r]; k[o] = ak[r]; v[o] = av[r];
    }
}

// ---- Kernel B: 4 rows/block: stream + softmax + PV + Wo + res + LN2 -------
__global__ __launch_bounds__(256) void scores_pv_kernel(
    const float* __restrict__ pe,
    const float* __restrict__ mask,
    const float* __restrict__ q, const float* __restrict__ k,
    const float* __restrict__ v,
    const float* __restrict__ x,
    const float* __restrict__ Wo, const float* __restrict__ bo,
    const float* __restrict__ ln2_g, const float* __restrict__ ln2_b,
    float* __restrict__ x2g, float* __restrict__ xn2g)
{
    const int bid  = blockIdx.x;                    // 0..1023
    const int blk  = (bid & 7) * 128 + (bid >> 3);  // XCD-chunked, bijective
    const int row0 = blk * 4;
    const int bb   = row0 >> 8;
    const int t    = threadIdx.x;                   // 0..255

    __shared__ __half sc[4][HEADS][264];   // 16.9 KB scores->probs
    __shared__ float msk[4][NN];           // 4 KB (prefetched, hides in stream)
    __shared__ float red4[4][4][EMBED];    // 8 KB PV wave partials
    __shared__ float ctx[4][EMBED];        // 2 KB
    __shared__ float wred[2][4][EMBED];    // 4 KB Wo c-half partials
    __shared__ float x2s[4][EMBED];        // 2 KB

    const int g = t >> 5;            // 0..7
    const int l = t & 31;            // lane covers dims 4l..4l+3

    // prefetch mask for 4 rows (overlaps with stream below)
    #pragma unroll
    for (int r = 0; r < 4; ++r)
        msk[r][t] = mask[(size_t)(row0 + r) * NN + t];

    // q fragments for 4 rows
    floatx4 q4[4];
    #pragma unroll
    for (int r = 0; r < 4; ++r)
        q4[r] = *reinterpret_cast<const floatx4*>(q + (size_t)(row0 + r) * EMBED + 4 * l);

    const size_t pe_base = (size_t)row0 * NN * EMBED;
    const size_t k_row   = (size_t)bb * NN * EMBED;
    const int rot = blk & 31;

    // ---- P1: stream pe for 4 rows; k loaded once per j --------------------
    #pragma unroll 4
    for (int jt0 = 0; jt0 < 32; ++jt0) {
        const int jt = (jt0 + rot) & 31;
        const int j  = jt * 8 + g;
        const floatx4 k4 = *reinterpret_cast<const floatx4*>(k + k_row + (size_t)j * EMBED + 4 * l);
        #pragma unroll
        for (int r = 0; r < 4; ++r) {
            const floatx4 p4 = __builtin_nontemporal_load(
                reinterpret_cast<const floatx4*>(pe + pe_base + ((size_t)r * NN + j) * EMBED + 4 * l));
            const floatx4 sum = k4 + p4;
            float s = q4[r].x * sum.x + q4[r].y * sum.y + q4[r].z * sum.z + q4[r].w * sum.w;
            s += __shfl_xor(s, 1);
            s += __shfl_xor(s, 2);
            if ((l & 3) == 0) sc[r][l >> 2][j] = __float2half(s * 0.25f);
        }
    }
    __syncthreads();

    // ---- P2: softmax; group g = head g, loop rows -------------------------
    #pragma unroll
    for (int r = 0; r < 4; ++r) {
        float vals[8];
        float m = -1e30f;
        #pragma unroll
        for (int rr = 0; rr < 8; ++rr) {
            vals[rr] = __half2float(sc[r][g][l + 32 * rr]) + msk[r][l + 32 * rr];
            m = fmaxf(m, vals[rr]);
        }
        #pragma unroll
        for (int off = 16; off >= 1; off >>= 1) m = fmaxf(m, __shfl_xor(m, off));
        float ssum = 0.f;
        #pragma unroll
        for (int rr = 0; rr < 8; ++rr) { float e2 = __expf(vals[rr] - m); vals[rr] = e2; ssum += e2; }
        #pragma unroll
        for (int off = 16; off >= 1; off >>= 1) ssum += __shfl_xor(ssum, off);
        const float inv = 1.0f / ssum;
        #pragma unroll
        for (int rr = 0; rr < 8; ++rr) sc[r][g][l + 32 * rr] = __float2half(vals[rr] * inv);
    }
    __syncthreads();

    // ---- P3: PV. thread (e4, seg): v loaded once, reused x4 rows ----------
    {
        const int e4  = t & 31;
        const int seg = t >> 5;
        const int h   = e4 >> 2;
        floatx4 acc0 = {0,0,0,0}, acc1 = acc0, acc2 = acc0, acc3 = acc0;
        const float* vb = v + ((size_t)(bb * NN + seg * 32)) * EMBED + 4 * e4;
        #pragma unroll 4
        for (int jj = 0; jj < 32; ++jj) {
            const floatx4 v4 = *reinterpret_cast<const floatx4*>(vb + (size_t)jj * EMBED);
            acc0 += __half2float(sc[0][h][seg * 32 + jj]) * v4;
            acc1 += __half2float(sc[1][h][seg * 32 + jj]) * v4;
            acc2 += __half2float(sc[2][h][seg * 32 + jj]) * v4;
            acc3 += __half2float(sc[3][h][seg * 32 + jj]) * v4;
        }
        acc0.x += __shfl_xor(acc0.x, 32); acc0.y += __shfl_xor(acc0.y, 32);
        acc0.z += __shfl_xor(acc0.z, 32); acc0.w += __shfl_xor(acc0.w, 32);
        acc1.x += __shfl_xor(acc1.x, 32); acc1.y += __shfl_xor(acc1.y, 32);
        acc1.z += __shfl_xor(acc1.z, 32); acc1.w += __shfl_xor(acc1.w, 32);
        acc2.x += __shfl_xor(acc2.x, 32); acc2.y += __shfl_xor(acc2.y, 32);
        acc2.z += __shfl_xor(acc2.z, 32); acc2.w += __shfl_xor(acc2.w, 32);
        acc3.x += __shfl_xor(acc3.x, 32); acc3.y += __shfl_xor(acc3.y, 32);
        acc3.z += __shfl_xor(acc3.z, 32); acc3.w += __shfl_xor(acc3.w, 32);
        if ((t & 63) < 32) {
            const int w = t >> 6;
            *reinterpret_cast<floatx4*>(&red4[w][0][4 * e4]) = acc0;
            *reinterpret_cast<floatx4*>(&red4[w][1][4 * e4]) = acc1;
            *reinterpret_cast<floatx4*>(&red4[w][2][4 * e4]) = acc2;
            *reinterpret_cast<floatx4*>(&red4[w][3][4 * e4]) = acc3;
        }
    }
    __syncthreads();
    {
        #pragma unroll
        for (int rr = 0; rr < 2; ++rr) {
            const int idx = t + 256 * rr;      // 0..511 = r*128 + e
            const int r = idx >> 7, e = idx & 127;
            ctx[r][e] = red4[0][r][e] + red4[1][r][e] + red4[2][r][e] + red4[3][r][e];
        }
    }
    __syncthreads();

    // ---- P4: Wo. thread (e, rp = c-half); Wo element reused x4 rows -------
    {
        const int e = t & 127, rp = t >> 7;
        float a0 = 0.f, a1 = 0.f, a2 = 0.f, a3 = 0.f;
        const float* Wob = Wo + rp * 64 * EMBED + e;
        #pragma unroll 8
        for (int cc = 0; cc < 64; ++cc) {
            const float w = Wob[(size_t)cc * EMBED];
            a0 += ctx[0][rp * 64 + cc] * w;
            a1 += ctx[1][rp * 64 + cc] * w;
            a2 += ctx[2][rp * 64 + cc] * w;
            a3 += ctx[3][rp * 64 + cc] * w;
        }
        wred[rp][0][e] = a0; wred[rp][1][e] = a1;
        wred[rp][2][e] = a2; wred[rp][3][e] = a3;
    }
    __syncthreads();

    // ---- P5: combine + bias + residual -> x2 ------------------------------
    {
        #pragma unroll
        for (int rr = 0; rr < 2; ++rr) {
            const int idx = t + 256 * rr;
            const int r = idx >> 7, e = idx & 127;
            const float a2 = wred[0][r][e] + wred[1][r][e] + bo[e]
                           + x[(size_t)(row0 + r) * EMBED + e];
            x2s[r][e] = a2;
            x2g[(size_t)(row0 + r) * EMBED + e] = a2;
        }
    }
    __syncthreads();

    // ---- P6: LN2. wave w handles row w -------------------------------------
    {
        const int wid = t >> 6, l64 = t & 63;
        const float v0 = x2s[wid][l64], v1 = x2s[wid][l64 + 64];
        float s  = v0 + v1;
        float sq = v0 * v0 + v1 * v1;
        #pragma unroll
        for (int off = 32; off >= 1; off >>= 1) {
            s  += __shfl_xor(s, off);
            sq += __shfl_xor(sq, off);
        }
        const float mu  = s * (1.0f / EMBED);
        const float var = sq * (1.0f / EMBED) - mu * mu;
        const float rs  = rsqrtf(var + 1e-5f);
        xn2g[(size_t)(row0 + wid) * EMBED + l64] =
            (v0 - mu) * rs * ln2_g[l64] + ln2_b[l64];
        xn2g[(size_t)(row0 + wid) * EMBED + 64 + l64] =
            (v1 - mu) * rs * ln2_g[l64 + 64] + ln2_b[l64 + 64];
    }
}

// ---- Kernel C2: FFN + residual (8 rows/block, 512 threads) ----------------
// Quarter-split FFN2 + LDS reduce: 256 L2 loads/thread, 32 waves/CU.
__global__ __launch_bounds__(512) void ffn_kernel(
    const float* __restrict__ x2g,
    const float* __restrict__ xn2g,
    const float* __restrict__ W1, const float* __restrict__ b1,
    const float* __restrict__ W2, const float* __restrict__ b2,
    float* __restrict__ out)
{
    const int row0 = blockIdx.x * 8;     // 512 blocks
    const int t    = threadIdx.x;        // 0..511

    __shared__ float xn2s[8][EMBED];     // 4 KB
    __shared__ float hb[8][FFN];         // 16 KB
    __shared__ float redf[4][8][EMBED];  // 16 KB

    if (t < 256) {
        const floatx4 v4 = *reinterpret_cast<const floatx4*>(
            xn2g + (size_t)row0 * EMBED + 4 * t);
        *reinterpret_cast<floatx4*>(&xn2s[0][0] + 4 * t) = v4;
    }
    __syncthreads();

    // FFN1: thread t -> hidden col t, all 8 rows (128 loads)
    {
        float h[8];
        const float c0 = b1[t];
        #pragma unroll
        for (int r = 0; r < 8; ++r) h[r] = c0;
        #pragma unroll 4
        for (int c = 0; c < EMBED; ++c) {
            const float w = W1[c * FFN + t];
            #pragma unroll
            for (int r = 0; r < 8; ++r) h[r] += xn2s[r][c] * w;
        }
        #pragma unroll
        for (int r = 0; r < 8; ++r) hb[r][t] = fmaxf(h[r], 0.f);
    }
    __syncthreads();

    // FFN2: thread (e = t&127, qd = t>>7) covers f-quarter, all 8 rows
    {
        const int e = t & 127, qd = t >> 7;
        float a[8];
        #pragma unroll
        for (int r = 0; r < 8; ++r) a[r] = 0.f;
        const float* W2b = W2 + (size_t)(qd * 128) * EMBED + e;
        #pragma unroll 4
        for (int ff = 0; ff < 128; ++ff) {
            const float w = W2b[(size_t)ff * EMBED];
            #pragma unroll
            for (int r = 0; r < 8; ++r) a[r] += hb[r][qd * 128 + ff] * w;
        }
        #pragma unroll
        for (int r = 0; r < 8; ++r) redf[qd][r][e] = a[r];
    }
    __syncthreads();

    // combine quarters + bias + residual
    {
        #pragma unroll
        for (int rr = 0; rr < 2; ++rr) {
            const int idx = t + 512 * rr;        // 0..1023 = r*128+e
            const int r = idx >> 7, e = idx & 127;
            out[(size_t)(row0 + r) * EMBED + e] =
                x2g[(size_t)(row0 + r) * EMBED + e] + b2[e]
                + redf[0][r][e] + redf[1][r][e] + redf[2][r][e] + redf[3][r][e];
        }
    }
}

extern "C" void kernel_launch(void* const* d_in, const int* in_sizes, int n_in,
                              void* d_out, int out_size, void* d_ws, size_t ws_size,
                              hipStream_t stream) {
    const float* x    = (const float*)d_in[0];
    const float* pe   = (const float*)d_in[1];
    const float* mask = (const float*)d_in[2];
    const float* ln1g = (const float*)d_in[3];
    const float* ln1b = (const float*)d_in[4];
    const float* Wq   = (const float*)d_in[5];
    const float* bq   = (const float*)d_in[6];
    const float* Wk   = (const float*)d_in[7];
    const float* bk   = (const float*)d_in[8];
    const float* Wv   = (const float*)d_in[9];
    const float* bv   = (const float*)d_in[10];
    const float* Wo   = (const float*)d_in[11];
    const float* bo   = (const float*)d_in[12];
    const float* ln2g = (const float*)d_in[13];
    const float* ln2b = (const float*)d_in[14];
    const float* W1   = (const float*)d_in[15];
    const float* b1   = (const float*)d_in[16];
    const float* W2   = (const float*)d_in[17];
    const float* b2   = (const float*)d_in[18];
    float* out = (float*)d_out;

    float* q    = (float*)d_ws;
    float* kk   = q    + (size_t)BB * NN * EMBED;
    float* vv   = kk   + (size_t)BB * NN * EMBED;
    float* x2g  = vv   + (size_t)BB * NN * EMBED;
    float* xn2g = x2g  + (size_t)BB * NN * EMBED;

    ln1_qkv_kernel<<<BB * NN / 8, 128, 0, stream>>>(x, ln1g, ln1b, Wq, bq, Wk, bk, Wv, bv, q, kk, vv);
    scores_pv_kernel<<<BB * NN / 4, 256, 0, stream>>>(pe, mask, q, kk, vv, x, Wo, bo,
                                                      ln2g, ln2b, x2g, xn2g);
    ffn_kernel<<<BB * NN / 8, 512, 0, stream>>>(x2g, xn2g, W1, b1, W2, b2, out);
}

// Round 14
// 153.144 us; speedup vs baseline: 1.5502x; 1.0214x over previous
//
#include <hip/hip_runtime.h>
#include <hip/hip_bf16.h>
#include <hip/hip_fp16.h>

#define EMBED 128
#define HEADS 8
#define DH 16
#define FFN 512
#define BB 16
#define NN 256

typedef float floatx4 __attribute__((ext_vector_type(4)));

// ---- Kernel A: LN1 + QKV, 8 rows/block (weights read once per 8 rows) -----
__global__ __launch_bounds__(128) void ln1_qkv_kernel(
    const float* __restrict__ x,
    const float* __restrict__ ln1_g, const float* __restrict__ ln1_b,
    const float* __restrict__ Wq, const float* __restrict__ bq,
    const float* __restrict__ Wk, const float* __restrict__ bk,
    const float* __restrict__ Wv, const float* __restrict__ bv,
    float* __restrict__ q, float* __restrict__ k, float* __restrict__ v)
{
    const int row0 = blockIdx.x * 8;     // 512 blocks
    const int t    = threadIdx.x;        // 0..127
    const int wv_  = t >> 6;             // wave 0..1
    const int l64  = t & 63;

    __shared__ float xn[8][EMBED];

    #pragma unroll
    for (int rr = 0; rr < 4; ++rr) {
        const int r = wv_ * 4 + rr;
        const float v0 = x[(size_t)(row0 + r) * EMBED + l64];
        const float v1 = x[(size_t)(row0 + r) * EMBED + 64 + l64];
        float s  = v0 + v1;
        float sq = v0 * v0 + v1 * v1;
        #pragma unroll
        for (int off = 32; off >= 1; off >>= 1) {
            s  += __shfl_xor(s, off);
            sq += __shfl_xor(sq, off);
        }
        const float mu  = s * (1.0f / EMBED);
        const float var = sq * (1.0f / EMBED) - mu * mu;
        const float rs  = rsqrtf(var + 1e-5f);
        xn[r][l64]      = (v0 - mu) * rs * ln1_g[l64]      + ln1_b[l64];
        xn[r][l64 + 64] = (v1 - mu) * rs * ln1_g[l64 + 64] + ln1_b[l64 + 64];
    }
    __syncthreads();

    const int e = t;
    float aq[8], ak[8], av[8];
    const float bqe = bq[e], bke = bk[e], bve = bv[e];
    #pragma unroll
    for (int r = 0; r < 8; ++r) { aq[r] = bqe; ak[r] = bke; av[r] = bve; }

    #pragma unroll 4
    for (int c = 0; c < EMBED; ++c) {
        const float wq = Wq[c * EMBED + e];
        const float wk = Wk[c * EMBED + e];
        const float wv2 = Wv[c * EMBED + e];
        #pragma unroll
        for (int r = 0; r < 8; ++r) {
            const float xc = xn[r][c];
            aq[r] += xc * wq;
            ak[r] += xc * wk;
            av[r] += xc * wv2;
        }
    }
    #pragma unroll
    for (int r = 0; r < 8; ++r) {
        const size_t o = (size_t)(row0 + r) * EMBED + e;
        q[o] = aq[r]; k[o] = ak[r]; v[o] = av[r];
    }
}

// ---- Kernel B: 4 rows/block, FULLY FUSED:
// stream + softmax + PV + Wo + res + LN2 + FFN + res -> out.
// LDS overlays (barrier-separated): sc->hb, msk->xn2. 36.5 KB, 4 blocks/CU.
typedef __half scrow_t[HEADS][264];

__global__ __launch_bounds__(256) void scores_pv_ffn_kernel(
    const float* __restrict__ pe,
    const float* __restrict__ mask,
    const float* __restrict__ q, const float* __restrict__ k,
    const float* __restrict__ v,
    const float* __restrict__ x,
    const float* __restrict__ Wo, const float* __restrict__ bo,
    const float* __restrict__ ln2_g, const float* __restrict__ ln2_b,
    const float* __restrict__ W1, const float* __restrict__ b1,
    const float* __restrict__ W2, const float* __restrict__ b2,
    float* __restrict__ out)
{
    const int bid  = blockIdx.x;                    // 0..1023
    const int blk  = (bid & 7) * 128 + (bid >> 3);  // XCD-chunked, bijective
    const int row0 = blk * 4;
    const int bb   = row0 >> 8;
    const int t    = threadIdx.x;                   // 0..255

    __shared__ __align__(16) unsigned char poolA[4 * sizeof(scrow_t)]; // 16.9 KB
    __shared__ __align__(16) unsigned char poolB[4 * NN * 4];          // 4 KB
    __shared__ float red4[4][4][EMBED];    // 8 KB PV wave partials
    __shared__ float ctx[4][EMBED];        // 2 KB
    __shared__ float wred[2][4][EMBED];    // 4 KB Wo / FFN2 partials
    __shared__ float x2s[4][EMBED];        // 2 KB

    scrow_t* sc = reinterpret_cast<scrow_t*>(poolA);            // phases 1-3
    float (*hb)[FFN] = reinterpret_cast<float (*)[FFN]>(poolA); // phase FFN1+
    float (*msk)[NN] = reinterpret_cast<float (*)[NN]>(poolB);  // phases 1-2
    float (*xn2)[EMBED] = reinterpret_cast<float (*)[EMBED]>(poolB); // P6+

    const int g = t >> 5;            // 0..7
    const int l = t & 31;            // lane covers dims 4l..4l+3

    // prefetch mask for 4 rows (rides the stream)
    #pragma unroll
    for (int r = 0; r < 4; ++r)
        msk[r][t] = mask[(size_t)(row0 + r) * NN + t];

    // q fragments for 4 rows
    floatx4 q4[4];
    #pragma unroll
    for (int r = 0; r < 4; ++r)
        q4[r] = *reinterpret_cast<const floatx4*>(q + (size_t)(row0 + r) * EMBED + 4 * l);

    const size_t pe_base = (size_t)row0 * NN * EMBED;
    const size_t k_row   = (size_t)bb * NN * EMBED;
    const int rot = blk & 31;

    // ---- P1: stream pe for 4 rows; k loaded once per j --------------------
    #pragma unroll 4
    for (int jt0 = 0; jt0 < 32; ++jt0) {
        const int jt = (jt0 + rot) & 31;
        const int j  = jt * 8 + g;
        const floatx4 k4 = *reinterpret_cast<const floatx4*>(k + k_row + (size_t)j * EMBED + 4 * l);
        #pragma unroll
        for (int r = 0; r < 4; ++r) {
            const floatx4 p4 = __builtin_nontemporal_load(
                reinterpret_cast<const floatx4*>(pe + pe_base + ((size_t)r * NN + j) * EMBED + 4 * l));
            const floatx4 sum = k4 + p4;
            float s = q4[r].x * sum.x + q4[r].y * sum.y + q4[r].z * sum.z + q4[r].w * sum.w;
            s += __shfl_xor(s, 1);
            s += __shfl_xor(s, 2);
            if ((l & 3) == 0) sc[r][l >> 2][j] = __float2half(s * 0.25f);
        }
    }
    __syncthreads();

    // ---- P2: softmax; group g = head g, loop rows -------------------------
    #pragma unroll
    for (int r = 0; r < 4; ++r) {
        float vals[8];
        float m = -1e30f;
        #pragma unroll
        for (int rr = 0; rr < 8; ++rr) {
            vals[rr] = __half2float(sc[r][g][l + 32 * rr]) + msk[r][l + 32 * rr];
            m = fmaxf(m, vals[rr]);
        }
        #pragma unroll
        for (int off = 16; off >= 1; off >>= 1) m = fmaxf(m, __shfl_xor(m, off));
        float ssum = 0.f;
        #pragma unroll
        for (int rr = 0; rr < 8; ++rr) { float e2 = __expf(vals[rr] - m); vals[rr] = e2; ssum += e2; }
        #pragma unroll
        for (int off = 16; off >= 1; off >>= 1) ssum += __shfl_xor(ssum, off);
        const float inv = 1.0f / ssum;
        #pragma unroll
        for (int rr = 0; rr < 8; ++rr) sc[r][g][l + 32 * rr] = __float2half(vals[rr] * inv);
    }
    __syncthreads();

    // ---- P3: PV. thread (e4, seg): v loaded once, reused x4 rows ----------
    {
        const int e4  = t & 31;
        const int seg = t >> 5;
        const int h   = e4 >> 2;
        floatx4 acc0 = {0,0,0,0}, acc1 = acc0, acc2 = acc0, acc3 = acc0;
        const float* vb = v + ((size_t)(bb * NN + seg * 32)) * EMBED + 4 * e4;
        #pragma unroll 4
        for (int jj = 0; jj < 32; ++jj) {
            const floatx4 v4 = *reinterpret_cast<const floatx4*>(vb + (size_t)jj * EMBED);
            acc0 += __half2float(sc[0][h][seg * 32 + jj]) * v4;
            acc1 += __half2float(sc[1][h][seg * 32 + jj]) * v4;
            acc2 += __half2float(sc[2][h][seg * 32 + jj]) * v4;
            acc3 += __half2float(sc[3][h][seg * 32 + jj]) * v4;
        }
        acc0.x += __shfl_xor(acc0.x, 32); acc0.y += __shfl_xor(acc0.y, 32);
        acc0.z += __shfl_xor(acc0.z, 32); acc0.w += __shfl_xor(acc0.w, 32);
        acc1.x += __shfl_xor(acc1.x, 32); acc1.y += __shfl_xor(acc1.y, 32);
        acc1.z += __shfl_xor(acc1.z, 32); acc1.w += __shfl_xor(acc1.w, 32);
        acc2.x += __shfl_xor(acc2.x, 32); acc2.y += __shfl_xor(acc2.y, 32);
        acc2.z += __shfl_xor(acc2.z, 32); acc2.w += __shfl_xor(acc2.w, 32);
        acc3.x += __shfl_xor(acc3.x, 32); acc3.y += __shfl_xor(acc3.y, 32);
        acc3.z += __shfl_xor(acc3.z, 32); acc3.w += __shfl_xor(acc3.w, 32);
        if ((t & 63) < 32) {
            const int w = t >> 6;
            *reinterpret_cast<floatx4*>(&red4[w][0][4 * e4]) = acc0;
            *reinterpret_cast<floatx4*>(&red4[w][1][4 * e4]) = acc1;
            *reinterpret_cast<floatx4*>(&red4[w][2][4 * e4]) = acc2;
            *reinterpret_cast<floatx4*>(&red4[w][3][4 * e4]) = acc3;
        }
    }
    __syncthreads();
    {
        #pragma unroll
        for (int rr = 0; rr < 2; ++rr) {
            const int idx = t + 256 * rr;      // 0..511 = r*128 + e
            const int r = idx >> 7, e = idx & 127;
            ctx[r][e] = red4[0][r][e] + red4[1][r][e] + red4[2][r][e] + red4[3][r][e];
        }
    }
    __syncthreads();

    // ---- P4: Wo. thread (e, rp = c-half); Wo element reused x4 rows -------
    {
        const int e = t & 127, rp = t >> 7;
        float a0 = 0.f, a1 = 0.f, a2 = 0.f, a3 = 0.f;
        const float* Wob = Wo + rp * 64 * EMBED + e;
        #pragma unroll 8
        for (int cc = 0; cc < 64; ++cc) {
            const float w = Wob[(size_t)cc * EMBED];
            a0 += ctx[0][rp * 64 + cc] * w;
            a1 += ctx[1][rp * 64 + cc] * w;
            a2 += ctx[2][rp * 64 + cc] * w;
            a3 += ctx[3][rp * 64 + cc] * w;
        }
        wred[rp][0][e] = a0; wred[rp][1][e] = a1;
        wred[rp][2][e] = a2; wred[rp][3][e] = a3;
    }
    __syncthreads();

    // ---- P5: combine + bias + residual -> x2s ------------------------------
    {
        #pragma unroll
        for (int rr = 0; rr < 2; ++rr) {
            const int idx = t + 256 * rr;
            const int r = idx >> 7, e = idx & 127;
            x2s[r][e] = wred[0][r][e] + wred[1][r][e] + bo[e]
                      + x[(size_t)(row0 + r) * EMBED + e];
        }
    }
    __syncthreads();

    // ---- P6: LN2. wave w handles row w; xn2 overlays dead msk -------------
    {
        const int wid = t >> 6, l64 = t & 63;
        const float v0 = x2s[wid][l64], v1 = x2s[wid][l64 + 64];
        float s  = v0 + v1;
        float sq = v0 * v0 + v1 * v1;
        #pragma unroll
        for (int off = 32; off >= 1; off >>= 1) {
            s  += __shfl_xor(s, off);
            sq += __shfl_xor(sq, off);
        }
        const float mu  = s * (1.0f / EMBED);
        const float var = sq * (1.0f / EMBED) - mu * mu;
        const float rs  = rsqrtf(var + 1e-5f);
        xn2[wid][l64]      = (v0 - mu) * rs * ln2_g[l64]      + ln2_b[l64];
        xn2[wid][l64 + 64] = (v1 - mu) * rs * ln2_g[l64 + 64] + ln2_b[l64 + 64];
    }
    __syncthreads();

    // ---- P7: FFN1. thread t -> hidden cols {t, t+256}; hb overlays sc -----
    {
        float h0[4], h1[4];
        const float c0 = b1[t], c1 = b1[t + 256];
        #pragma unroll
        for (int r = 0; r < 4; ++r) { h0[r] = c0; h1[r] = c1; }
        #pragma unroll 4
        for (int c = 0; c < EMBED; ++c) {
            const float w0 = W1[c * FFN + t];
            const float w1 = W1[c * FFN + t + 256];
            #pragma unroll
            for (int r = 0; r < 4; ++r) {
                const float xc = xn2[r][c];
                h0[r] += xc * w0;
                h1[r] += xc * w1;
            }
        }
        #pragma unroll
        for (int r = 0; r < 4; ++r) {
            hb[r][t]       = fmaxf(h0[r], 0.f);
            hb[r][t + 256] = fmaxf(h1[r], 0.f);
        }
    }
    __syncthreads();

    // ---- P8: FFN2. thread (e, rp = f-half); wred reused for partials ------
    {
        const int e = t & 127, rp = t >> 7;
        float a0 = 0.f, a1 = 0.f, a2 = 0.f, a3 = 0.f;
        const float* W2b = W2 + (size_t)(rp * 256) * EMBED + e;
        #pragma unroll 8
        for (int ff = 0; ff < 256; ++ff) {
            const float w = W2b[(size_t)ff * EMBED];
            a0 += hb[0][rp * 256 + ff] * w;
            a1 += hb[1][rp * 256 + ff] * w;
            a2 += hb[2][rp * 256 + ff] * w;
            a3 += hb[3][rp * 256 + ff] * w;
        }
        wred[rp][0][e] = a0; wred[rp][1][e] = a1;
        wred[rp][2][e] = a2; wred[rp][3][e] = a3;
    }
    __syncthreads();

    // ---- P9: combine + bias + residual -> out ------------------------------
    {
        #pragma unroll
        for (int rr = 0; rr < 2; ++rr) {
            const int idx = t + 256 * rr;
            const int r = idx >> 7, e = idx & 127;
            out[(size_t)(row0 + r) * EMBED + e] =
                x2s[r][e] + b2[e] + wred[0][r][e] + wred[1][r][e];
        }
    }
}

extern "C" void kernel_launch(void* const* d_in, const int* in_sizes, int n_in,
                              void* d_out, int out_size, void* d_ws, size_t ws_size,
                              hipStream_t stream) {
    const float* x    = (const float*)d_in[0];
    const float* pe   = (const float*)d_in[1];
    const float* mask = (const float*)d_in[2];
    const float* ln1g = (const float*)d_in[3];
    const float* ln1b = (const float*)d_in[4];
    const float* Wq   = (const float*)d_in[5];
    const float* bq   = (const float*)d_in[6];
    const float* Wk   = (const float*)d_in[7];
    const float* bk   = (const float*)d_in[8];
    const float* Wv   = (const float*)d_in[9];
    const float* bv   = (const float*)d_in[10];
    const float* Wo   = (const float*)d_in[11];
    const float* bo   = (const float*)d_in[12];
    const float* ln2g = (const float*)d_in[13];
    const float* ln2b = (const float*)d_in[14];
    const float* W1   = (const float*)d_in[15];
    const float* b1   = (const float*)d_in[16];
    const float* W2   = (const float*)d_in[17];
    const float* b2   = (const float*)d_in[18];
    float* out = (float*)d_out;

    float* q  = (float*)d_ws;
    float* kk = q  + (size_t)BB * NN * EMBED;
    float* vv = kk + (size_t)BB * NN * EMBED;

    ln1_qkv_kernel<<<BB * NN / 8, 128, 0, stream>>>(x, ln1g, ln1b, Wq, bq, Wk, bk, Wv, bv, q, kk, vv);
    scores_pv_ffn_kernel<<<BB * NN / 4, 256, 0, stream>>>(pe, mask, q, kk, vv, x,
                                                          Wo, bo, ln2g, ln2b,
                                                          W1, b1, W2, b2, out);
}